// Round 5
// baseline (656.912 us; speedup 1.0000x reference)
//
#include <hip/hip_runtime.h>
#include <hip/hip_bf16.h>
#include <math.h>

#define B_   4
#define T_   2048
#define C_   1024
#define H_   8
#define DH   128
#define DFF  4096
#define M_   (B_*T_)   // 8192 rows

typedef __attribute__((ext_vector_type(8))) short bf16x8;
typedef __attribute__((ext_vector_type(4))) float f32x4;
typedef __attribute__((ext_vector_type(2))) unsigned int u32x2;

// sqrt(128) * log2(e): scores computed directly in exp2 domain
#define SC2 16.32223094f

__device__ __forceinline__ unsigned short f2bf(float x) {
  union { float f; unsigned u; } v; v.f = x;
  return (unsigned short)((v.u + 0x7fffu + ((v.u >> 16) & 1u)) >> 16);
}
__device__ __forceinline__ float bf2f(unsigned short h) {
  union { unsigned u; float f; } v; v.u = ((unsigned)h) << 16; return v.f;
}

__device__ __forceinline__ f32x4 mfma_bf16(bf16x8 a, bf16x8 b, f32x4 c) {
  return __builtin_amdgcn_mfma_f32_16x16x32_bf16(a, b, c, 0, 0, 0);
}

// async global->LDS, 16B per lane; HW places lane i at wave-base + i*16
__device__ __forceinline__ void gll16(const void* g, void* l) {
  __builtin_amdgcn_global_load_lds((const __attribute__((address_space(1))) void*)g,
                                   (__attribute__((address_space(3))) void*)l,
                                   16, 0, 0);
}

// ---------------------------------------------------------------------------
// LayerNorm: one block per row, 256 threads; emits hi/lo split bf16.
// ---------------------------------------------------------------------------
__global__ __launch_bounds__(256) void ln_kernel(const float* __restrict__ in,
                                                 const float* __restrict__ g,
                                                 const float* __restrict__ bb,
                                                 unsigned short* __restrict__ h_hi,
                                                 unsigned short* __restrict__ h_lo) {
  __shared__ float red[8];
  const int row = blockIdx.x;
  const int tid = threadIdx.x;
  const float* p = in + (size_t)row * C_;
  const float4 xv = *(const float4*)(p + (tid << 2));
  float s  = xv.x + xv.y + xv.z + xv.w;
  float sq = xv.x*xv.x + xv.y*xv.y + xv.z*xv.z + xv.w*xv.w;
  #pragma unroll
  for (int off = 32; off > 0; off >>= 1) {
    s  += __shfl_xor(s, off);
    sq += __shfl_xor(sq, off);
  }
  if ((tid & 63) == 0) { red[(tid >> 6) * 2] = s; red[(tid >> 6) * 2 + 1] = sq; }
  __syncthreads();
  s  = red[0] + red[2] + red[4] + red[6];
  sq = red[1] + red[3] + red[5] + red[7];
  const float mu  = s * (1.0f / C_);
  const float var = sq * (1.0f / C_) - mu * mu;
  const float rs  = rsqrtf(var + 1e-5f);
  const float4 gv = *(const float4*)(g  + (tid << 2));
  const float4 bv = *(const float4*)(bb + (tid << 2));
  float ov[4];
  ov[0] = (xv.x - mu) * rs * gv.x + bv.x;
  ov[1] = (xv.y - mu) * rs * gv.y + bv.y;
  ov[2] = (xv.z - mu) * rs * gv.z + bv.z;
  ov[3] = (xv.w - mu) * rs * gv.w + bv.w;
  ushort4 hv, lv;
  unsigned short* hp = (unsigned short*)&hv;
  unsigned short* lp = (unsigned short*)&lv;
  #pragma unroll
  for (int j = 0; j < 4; ++j) {
    hp[j] = f2bf(ov[j]);
    lp[j] = f2bf(ov[j] - bf2f(hp[j]));
  }
  *(ushort4*)(h_hi + (size_t)row * C_ + (tid << 2)) = hv;
  *(ushort4*)(h_lo + (size_t)row * C_ + (tid << 2)) = lv;
}

// ---------------------------------------------------------------------------
// Weight converters (transpose to n-major k-contiguous bf16).
// ---------------------------------------------------------------------------
__global__ __launch_bounds__(256) void cvt_t_kernel(const float* __restrict__ in,
                                                    unsigned short* __restrict__ out,
                                                    int R, int CC) {
  __shared__ float tile[32][33];
  const int r0 = blockIdx.y << 5, c0 = blockIdx.x << 5;
  const int tr = threadIdx.x >> 3, tc4 = (threadIdx.x & 7) << 2;
  const float4 vv = *(const float4*)(in + (size_t)(r0 + tr) * CC + c0 + tc4);
  tile[tr][tc4+0] = vv.x; tile[tr][tc4+1] = vv.y;
  tile[tr][tc4+2] = vv.z; tile[tr][tc4+3] = vv.w;
  __syncthreads();
  ushort4 o;
  o.x = f2bf(tile[tc4+0][tr]); o.y = f2bf(tile[tc4+1][tr]);
  o.z = f2bf(tile[tc4+2][tr]); o.w = f2bf(tile[tc4+3][tr]);
  *(ushort4*)(out + (size_t)(c0 + tr) * R + r0 + tc4) = o;
}

// split hi/lo transpose for wq/wk/wv: in [H][C][DH] -> out[z][DH][C], z=which*8+h
__global__ __launch_bounds__(256) void cvt_qkv_kernel(const float* __restrict__ wq,
                                                      const float* __restrict__ wk,
                                                      const float* __restrict__ wv,
                                                      unsigned short* __restrict__ wt_hi,
                                                      unsigned short* __restrict__ wt_lo) {
  const int z = blockIdx.z;
  const int which = z >> 3, head = z & 7;
  const float* in = (which == 0 ? wq : (which == 1 ? wk : wv)) + (size_t)head * C_ * DH;
  unsigned short* oh = wt_hi + (size_t)z * DH * C_;
  unsigned short* ol = wt_lo + (size_t)z * DH * C_;
  __shared__ float tile[32][33];
  const int r0 = blockIdx.y << 5, c0 = blockIdx.x << 5;   // r over C, c over DH
  const int tr = threadIdx.x >> 3, tc4 = (threadIdx.x & 7) << 2;
  const float4 vv = *(const float4*)(in + (size_t)(r0 + tr) * DH + c0 + tc4);
  tile[tr][tc4+0] = vv.x; tile[tr][tc4+1] = vv.y;
  tile[tr][tc4+2] = vv.z; tile[tr][tc4+3] = vv.w;
  __syncthreads();
  ushort4 hv, lv;
  unsigned short* hp = (unsigned short*)&hv;
  unsigned short* lp = (unsigned short*)&lv;
  #pragma unroll
  for (int j = 0; j < 4; ++j) {
    const float val = tile[tc4+j][tr];
    hp[j] = f2bf(val);
    lp[j] = f2bf(val - bf2f(hp[j]));
  }
  *(ushort4*)(oh + (size_t)(c0 + tr) * C_ + r0 + tc4) = hv;
  *(ushort4*)(ol + (size_t)(c0 + tr) * C_ + r0 + tc4) = lv;
}

// ---------------------------------------------------------------------------
// LDS tile swizzle (all MFMA-staged tiles): rows are 64B (32 bf16 of k).
// LDS[r][c] = G[r][c ^ ((r>>1 & 3)<<3)], applied by swizzling the gll16
// GLOBAL source column (dest stays linear - global_load_lds requirement).
// ---------------------------------------------------------------------------

// ---------------------------------------------------------------------------
// Single-buffered split-precision GEMM (qkm only): 128x128 tile, BK=32,
// 4 waves. TERMS=3: Ah*Bh + Ah*Bl + Al*Bh.
// ---------------------------------------------------------------------------
__device__ __forceinline__ void gemm128_split3(
    const unsigned short* __restrict__ Ah, const unsigned short* __restrict__ Al,
    int lda,
    const unsigned short* __restrict__ Bh, const unsigned short* __restrict__ Bl,
    int ldb, int K, f32x4 (&acc)[4][4],
    unsigned short* AhS, unsigned short* AlS,
    unsigned short* BhS, unsigned short* BlS) {
  const int tid  = threadIdx.x;
  const int w    = tid >> 6;
  const int lane = tid & 63;
  const int l15  = lane & 15, quad = lane >> 4;
  const int srow = lane >> 2;
  const int skc  = ((lane & 3) << 3) ^ (((srow >> 1) & 3) << 3);  // pre-swizzled src col
  const int wm = w & 1, wn = w >> 1;
  const int ro = ((quad ^ ((l15 >> 1) & 3)) << 3);                // swizzled read col

  for (int k0 = 0; k0 < K; k0 += 32) {
    __syncthreads();
    #pragma unroll
    for (int i = 0; i < 2; ++i) {
      const int seg  = w * 2 + i;
      const int r    = seg * 16 + srow;
      const int lofs = seg * 512 + lane * 8;
      gll16(Ah + (size_t)r * lda + k0 + skc, AhS + lofs);
      gll16(Bh + (size_t)r * ldb + k0 + skc, BhS + lofs);
      gll16(Al + (size_t)r * lda + k0 + skc, AlS + lofs);
      gll16(Bl + (size_t)r * ldb + k0 + skc, BlS + lofs);
    }
    __syncthreads();
    bf16x8 aH[4], bH[4], aL[4], bL[4];
    #pragma unroll
    for (int t = 0; t < 4; ++t) {
      aH[t] = *(const bf16x8*)&AhS[(wm * 64 + t * 16 + l15) * 32 + ro];
      bH[t] = *(const bf16x8*)&BhS[(wn * 64 + t * 16 + l15) * 32 + ro];
      aL[t] = *(const bf16x8*)&AlS[(wm * 64 + t * 16 + l15) * 32 + ro];
      bL[t] = *(const bf16x8*)&BlS[(wn * 64 + t * 16 + l15) * 32 + ro];
    }
    #pragma unroll
    for (int rt = 0; rt < 4; ++rt)
      #pragma unroll
      for (int ct = 0; ct < 4; ++ct) {
        acc[rt][ct] = mfma_bf16(aL[rt], bH[ct], acc[rt][ct]);
        acc[rt][ct] = mfma_bf16(aH[rt], bL[ct], acc[rt][ct]);
        acc[rt][ct] = mfma_bf16(aH[rt], bH[ct], acc[rt][ct]);
      }
  }
}

// ---------------------------------------------------------------------------
// Double-buffered bf16 GEMM (vm/ff1/ff2): pipelined stage-after-barrier.
// ---------------------------------------------------------------------------
__device__ __forceinline__ void gemm128_db(
    const unsigned short* __restrict__ Ah, int lda,
    const unsigned short* __restrict__ Bh, int ldb, int K, f32x4 (&acc)[4][4],
    unsigned short (&AS0)[4096], unsigned short (&AS1)[4096],
    unsigned short (&BS0)[4096], unsigned short (&BS1)[4096]) {
  const int tid  = threadIdx.x;
  const int w    = tid >> 6;
  const int lane = tid & 63;
  const int l15  = lane & 15, quad = lane >> 4;
  const int srow = lane >> 2;
  const int skc  = ((lane & 3) << 3) ^ (((srow >> 1) & 3) << 3);
  const int wm = w & 1, wn = w >> 1;
  const int ro = ((quad ^ ((l15 >> 1) & 3)) << 3);
  const int Km = K - 1;

  auto STG = [&](int k0, unsigned short* A, unsigned short* B) {
    #pragma unroll
    for (int i = 0; i < 2; ++i) {
      const int seg  = w * 2 + i;
      const int r    = seg * 16 + srow;
      const int lofs = seg * 512 + lane * 8;
      gll16(Ah + (size_t)r * lda + k0 + skc, A + lofs);
      gll16(Bh + (size_t)r * ldb + k0 + skc, B + lofs);
    }
  };
  auto CMP = [&](const unsigned short* A, const unsigned short* B) {
    bf16x8 aH[4], bH[4];
    #pragma unroll
    for (int t = 0; t < 4; ++t) {
      aH[t] = *(const bf16x8*)&A[(wm * 64 + t * 16 + l15) * 32 + ro];
      bH[t] = *(const bf16x8*)&B[(wn * 64 + t * 16 + l15) * 32 + ro];
    }
    #pragma unroll
    for (int rt = 0; rt < 4; ++rt)
      #pragma unroll
      for (int ct = 0; ct < 4; ++ct)
        acc[rt][ct] = mfma_bf16(aH[rt], bH[ct], acc[rt][ct]);
  };

  STG(0, AS0, BS0);
  for (int k0 = 0; k0 < K; k0 += 64) {
    __syncthreads();
    STG((k0 + 32) & Km, AS1, BS1);
    CMP(AS0, BS0);
    __syncthreads();
    STG((k0 + 64) & Km, AS0, BS0);
    CMP(AS1, BS1);
  }
}

// ---------------------------------------------------------------------------
// QK projection (split precision). grid = (M/128=64, 2*H=16).
// which==0: q out [bh][t][d] bf16 hi/lo, PRE-SCALED by SC2 (exp2-domain).
// which==1: k out tile-image [bh][64 kt][4 kc][32 key][32 d-swz] bf16 hi/lo,
//           d column pre-swizzled: d' = d ^ ((key>>1 & 3)<<3).
// ---------------------------------------------------------------------------
__global__ __launch_bounds__(256) void qkm_kernel(const unsigned short* __restrict__ h_hi,
                                                  const unsigned short* __restrict__ h_lo,
                                                  const unsigned short* __restrict__ wt_hi,
                                                  const unsigned short* __restrict__ wt_lo,
                                                  unsigned short* __restrict__ q_hi,
                                                  unsigned short* __restrict__ q_lo,
                                                  unsigned short* __restrict__ k_hi,
                                                  unsigned short* __restrict__ k_lo) {
  __shared__ __align__(16) unsigned short AhS[4096], AlS[4096];
  __shared__ __align__(16) unsigned short BhS[4096], BlS[4096];
  const int m0 = blockIdx.x << 7;
  const int z  = blockIdx.y;
  const int which = z >> 3, head = z & 7;
  f32x4 acc[4][4];
  #pragma unroll
  for (int i = 0; i < 4; ++i)
    #pragma unroll
    for (int j = 0; j < 4; ++j)
      #pragma unroll
      for (int r = 0; r < 4; ++r) acc[i][j][r] = 0.f;
  gemm128_split3(h_hi + (size_t)m0 * C_, h_lo + (size_t)m0 * C_, C_,
                 wt_hi + (size_t)z * DH * C_, wt_lo + (size_t)z * DH * C_, C_,
                 C_, acc, AhS, AlS, BhS, BlS);
  const int lane = threadIdx.x & 63, w = threadIdx.x >> 6;
  const int l15 = lane & 15, quad = lane >> 4;
  const int wm = w & 1, wn = w >> 1;
  const int bh = (m0 >> 11) * H_ + head;
  const int tbase = (m0 & (T_ - 1)) + wm * 64 + quad * 4;
  if (which == 0) {
    #pragma unroll
    for (int rt = 0; rt < 4; ++rt)
      #pragma unroll
      for (int ct = 0; ct < 4; ++ct) {
        const int d = wn * 64 + ct * 16 + l15;
        #pragma unroll
        for (int r = 0; r < 4; ++r) {
          const int t = tbase + rt * 16 + r;
          const float val = acc[rt][ct][r] * SC2;
          const unsigned short hb = f2bf(val);
          const size_t idx = ((size_t)bh * T_ + t) * DH + d;
          q_hi[idx] = hb;
          q_lo[idx] = f2bf(val - bf2f(hb));
        }
      }
  } else {
    #pragma unroll
    for (int rt = 0; rt < 4; ++rt)
      #pragma unroll
      for (int ct = 0; ct < 4; ++ct) {
        const int d = wn * 64 + ct * 16 + l15;
        #pragma unroll
        for (int r = 0; r < 4; ++r) {
          const int t = tbase + rt * 16 + r;
          const int tt = t & 31;
          const float val = acc[rt][ct][r];
          const unsigned short hb = f2bf(val);
          const size_t idx = (((size_t)bh * 64 + (t >> 5)) * 4 + (d >> 5)) * 1024
                           + (size_t)tt * 32 + ((d & 31) ^ (((tt >> 1) & 3) << 3));
          k_hi[idx] = hb;
          k_lo[idx] = f2bf(val - bf2f(hb));
        }
      }
  }
}

// ---------------------------------------------------------------------------
// V projection (plain bf16). grid = (M/128=64, H=8).
// v out tile-image [bh][64 kt][128 d][32 key-swz], key' = key ^ ((d>>1 &3)<<3).
// ---------------------------------------------------------------------------
__global__ __launch_bounds__(256) void vm_kernel(const unsigned short* __restrict__ h_hi,
                                                 const unsigned short* __restrict__ wv_hi,
                                                 unsigned short* __restrict__ vimg) {
  __shared__ __align__(16) unsigned short AS0[4096], AS1[4096];
  __shared__ __align__(16) unsigned short BS0[4096], BS1[4096];
  const int m0 = blockIdx.x << 7;
  const int head = blockIdx.y;
  f32x4 acc[4][4];
  #pragma unroll
  for (int i = 0; i < 4; ++i)
    #pragma unroll
    for (int j = 0; j < 4; ++j)
      #pragma unroll
      for (int r = 0; r < 4; ++r) acc[i][j][r] = 0.f;
  gemm128_db(h_hi + (size_t)m0 * C_, C_,
             wv_hi + (size_t)(16 + head) * DH * C_, C_,
             C_, acc, AS0, AS1, BS0, BS1);
  const int lane = threadIdx.x & 63, w = threadIdx.x >> 6;
  const int l15 = lane & 15, quad = lane >> 4;
  const int wm = w & 1, wn = w >> 1;
  const int bh = (m0 >> 11) * H_ + head;
  #pragma unroll
  for (int rt = 0; rt < 4; ++rt)
    #pragma unroll
    for (int ct = 0; ct < 4; ++ct) {
      const int d  = wn * 64 + ct * 16 + l15;
      const int t0 = (m0 & (T_ - 1)) + wm * 64 + rt * 16 + quad * 4;
      const int key = (t0 & 31) ^ (((d >> 1) & 3) << 3);
      ushort4 pk;
      pk.x = f2bf(acc[rt][ct][0]); pk.y = f2bf(acc[rt][ct][1]);
      pk.z = f2bf(acc[rt][ct][2]); pk.w = f2bf(acc[rt][ct][3]);
      *(ushort4*)&vimg[(((size_t)bh * 64 + (t0 >> 5)) * 128 + d) * 32 + key] = pk;
    }
}

// ---------------------------------------------------------------------------
// FF1: ff1 = bf16(relu(h2 @ w1 + b1)).  grid = (DFF/128=32, M/128=64)
// ---------------------------------------------------------------------------
__global__ __launch_bounds__(256) void ff1_kernel(const unsigned short* __restrict__ h2,
                                                  const unsigned short* __restrict__ w1t,
                                                  const float* __restrict__ b1,
                                                  unsigned short* __restrict__ ff1) {
  __shared__ __align__(16) unsigned short AS0[4096], AS1[4096];
  __shared__ __align__(16) unsigned short BS0[4096], BS1[4096];
  const int n0 = blockIdx.x << 7;
  const int m0 = blockIdx.y << 7;
  f32x4 acc[4][4];
  #pragma unroll
  for (int i = 0; i < 4; ++i)
    #pragma unroll
    for (int j = 0; j < 4; ++j)
      #pragma unroll
      for (int r = 0; r < 4; ++r) acc[i][j][r] = 0.f;
  gemm128_db(h2 + (size_t)m0 * C_, C_,
             w1t + (size_t)n0 * C_, C_,
             C_, acc, AS0, AS1, BS0, BS1);
  const int lane = threadIdx.x & 63, w = threadIdx.x >> 6;
  const int l15 = lane & 15, quad = lane >> 4;
  const int wm = w & 1, wn = w >> 1;
  #pragma unroll
  for (int rt = 0; rt < 4; ++rt)
    #pragma unroll
    for (int ct = 0; ct < 4; ++ct) {
      const int n = n0 + wn * 64 + ct * 16 + l15;
      const float bias = b1[n];
      #pragma unroll
      for (int r = 0; r < 4; ++r) {
        const int m = m0 + wm * 64 + rt * 16 + quad * 4 + r;
        ff1[(size_t)m * DFF + n] = f2bf(fmaxf(acc[rt][ct][r] + bias, 0.f));
      }
    }
}

// ---------------------------------------------------------------------------
// FF2: out = ff1 @ w2 + b2 + xo.  grid = (C/128=8, M/128=64)
// ---------------------------------------------------------------------------
__global__ __launch_bounds__(256) void ff2_kernel(const unsigned short* __restrict__ ff1,
                                                  const unsigned short* __restrict__ w2t,
                                                  const float* __restrict__ b2,
                                                  const float* __restrict__ xo,
                                                  float* __restrict__ out) {
  __shared__ __align__(16) unsigned short AS0[4096], AS1[4096];
  __shared__ __align__(16) unsigned short BS0[4096], BS1[4096];
  const int n0 = blockIdx.x << 7;
  const int m0 = blockIdx.y << 7;
  f32x4 acc[4][4];
  #pragma unroll
  for (int i = 0; i < 4; ++i)
    #pragma unroll
    for (int j = 0; j < 4; ++j)
      #pragma unroll
      for (int r = 0; r < 4; ++r) acc[i][j][r] = 0.f;
  gemm128_db(ff1 + (size_t)m0 * DFF, DFF,
             w2t + (size_t)n0 * DFF, DFF,
             DFF, acc, AS0, AS1, BS0, BS1);
  const int lane = threadIdx.x & 63, w = threadIdx.x >> 6;
  const int l15 = lane & 15, quad = lane >> 4;
  const int wm = w & 1, wn = w >> 1;
  #pragma unroll
  for (int rt = 0; rt < 4; ++rt)
    #pragma unroll
    for (int ct = 0; ct < 4; ++ct) {
      const int n = n0 + wn * 64 + ct * 16 + l15;
      const float bias = b2[n];
      #pragma unroll
      for (int r = 0; r < 4; ++r) {
        const int m = m0 + wm * 64 + rt * 16 + quad * 4 + r;
        out[(size_t)m * C_ + n] = acc[rt][ct][r] + bias + xo[(size_t)m * C_ + n];
      }
    }
}

// ---------------------------------------------------------------------------
// MFMA flash attention, v5: SINGLE barrier per 64-key tile (T3-minimum
// 2-phase schedule). All of Kh/Kl/V double-buffered (96KB LDS, 1 block/CU,
// 8 waves). Per iter: B (drains stage issued a FULL iter ago); issue
// stage(j+1) into the non-current buffers (their last readers finished
// before B); QK^T(j); softmax(j); PV(j). Waves free-run between barriers —
// no per-phase lockstep. O^T accumulation, lane-local stats, in-reg P
// transpose, defer-max. grid = (T/128=16, B*H=32), 512 thr.
// ---------------------------------------------------------------------------
#define BQ 128

__global__ __launch_bounds__(512, 2) void attn_kernel(
    const unsigned short* __restrict__ q_hi, const unsigned short* __restrict__ q_lo,
    const unsigned short* __restrict__ k_hi, const unsigned short* __restrict__ k_lo,
    const unsigned short* __restrict__ vimg,
    const float* __restrict__ x, float* __restrict__ xo) {
  __shared__ __align__(16) unsigned short KhS[2][8192];  // [buf][2 sub][4 kc][32 key][32 d]
  __shared__ __align__(16) unsigned short KlS[2][8192];
  __shared__ __align__(16) unsigned short VtS[2][8192];  // [buf][2 sub][128 d][32 key]

  // XCD-aware remap (bijective, 512 blocks = 8 XCD x 64)
  const int bid   = blockIdx.x + (T_ / BQ) * blockIdx.y;
  const int chunk = bid >> 3;
  const int bh    = (bid & 7) * 4 + (chunk >> 4);
  const int qt0   = (chunk & 15) * BQ;

  const int tid  = threadIdx.x;
  const int w    = tid >> 6;           // 0..7
  const int lane = tid & 63;
  const int l15  = lane & 15;
  const int quad = lane >> 4;
  const int swz  = (l15 >> 1) & 3;     // LDS row-dependent slot swizzle key
  // P-transpose shuffle sources (same l15, cross-quad)
  const int sA   = ((quad & 1) << 5) + l15;   // quad_s = (quad&1)*2
  const int sB   = sA + 16;                   // quad_s = (quad&1)*2 + 1
  const int bsel = (quad >> 1) & 1;           // ct-parity select

  // ---- Q fragments (pre-scaled hi/lo bf16), 16 rows per wave ----
  bf16x8 Qh[4], Ql[4];
  {
    const int row = qt0 + w * 16 + l15;
    #pragma unroll
    for (int kc = 0; kc < 4; ++kc) {
      const size_t off = ((size_t)bh * T_ + row) * DH + kc * 32 + quad * 8;
      Qh[kc] = *(const bf16x8*)(q_hi + off);
      Ql[kc] = *(const bf16x8*)(q_lo + off);
    }
  }

  f32x4 O[8];      // O^T: lane holds O^T[d=16n+4quad+r][q=l15]
  #pragma unroll
  for (int n = 0; n < 8; ++n)
    #pragma unroll
    for (int r = 0; r < 4; ++r) O[n][r] = 0.f;
  float m_cur = -1e30f;   // running max for q = l15 (log2 units), lane-local
  float l_cur = 0.f;

  auto STAGE64 = [&](int jt) {   // tile jt&31 -> buffers jt&1 (6 gll16/thread)
    const size_t tb = ((size_t)bh * 64 + (jt & 31) * 2) * 4096;
    unsigned short* KH = &KhS[jt & 1][0];
    unsigned short* KL = &KlS[jt & 1][0];
    unsigned short* VT = &VtS[jt & 1][0];
    const int o = tid * 8;
    gll16(k_hi + tb + o, KH + o);
    gll16(k_hi + tb + 4096 + o, KH + 4096 + o);
    gll16(k_lo + tb + o, KL + o);
    gll16(k_lo + tb + 4096 + o, KL + 4096 + o);
    gll16(vimg + tb + o, VT + o);
    gll16(vimg + tb + 4096 + o, VT + 4096 + o);
  };

  STAGE64(0);

  for (int j = 0; j < T_ / 64; ++j) {          // 32 iters, 64 keys each
    __syncthreads();        // B: drains stage(j) issued a full iter ago;
                            //    all waves done reading buffers (j+1)&1
    STAGE64(j + 1);         // into non-current buffers; lands by next B

    // ---- S^T = K Q^T (3-term split). col=q=l15, row=key=16ct+4quad+r ----
    f32x4 S[4];
    #pragma unroll
    for (int ct = 0; ct < 4; ++ct)
      #pragma unroll
      for (int r = 0; r < 4; ++r) S[ct][r] = 0.f;
    {
      const unsigned short* KH = &KhS[j & 1][0];
      const unsigned short* KL = &KlS[j & 1][0];
      __builtin_amdgcn_s_setprio(1);
      #pragma unroll
      for (int sub = 0; sub < 2; ++sub)
        #pragma unroll
        for (int kc = 0; kc < 4; ++kc)
          #pragma unroll
          for (int c2 = 0; c2 < 2; ++c2) {
            const int o = sub * 4096 + kc * 1024 + (c2 * 16 + l15) * 32
                        + ((quad ^ swz) << 3);
            const bf16x8 kh = *(const bf16x8*)&KH[o];
            const bf16x8 kl = *(const bf16x8*)&KL[o];
            f32x4& Sr = S[sub * 2 + c2];
            Sr = mfma_bf16(kl, Qh[kc], Sr);
            Sr = mfma_bf16(kh, Ql[kc], Sr);
            Sr = mfma_bf16(kh, Qh[kc], Sr);
          }
      __builtin_amdgcn_s_setprio(0);
    }

    // ---- softmax(tile j): per-q max over 64 keys (lane-local stats) ----
    float mx = -1e30f;
    #pragma unroll
    for (int ct = 0; ct < 4; ++ct)
      mx = fmaxf(mx, fmaxf(fmaxf(S[ct][0], S[ct][1]), fmaxf(S[ct][2], S[ct][3])));
    mx = fmaxf(mx, __shfl_xor(mx, 16));
    mx = fmaxf(mx, __shfl_xor(mx, 32));

    // defer-max: rescale only when running max grew by > 8 (log2)
    if (__any(mx > m_cur + 8.f)) {
      const float mn = fmaxf(m_cur, mx);
      const float al = exp2f(m_cur - mn);
      m_cur = mn;
      l_cur *= al;
      #pragma unroll
      for (int n = 0; n < 8; ++n)
        #pragma unroll
        for (int r = 0; r < 4; ++r) O[n][r] *= al;
    }

    // P = exp2(S - m), truncation-pack pairs: pu[ct*2+h]
    unsigned pu[8];
    float rs = 0.f;
    #pragma unroll
    for (int ct = 0; ct < 4; ++ct) {
      const float p0 = exp2f(S[ct][0] - m_cur);
      const float p1 = exp2f(S[ct][1] - m_cur);
      const float p2 = exp2f(S[ct][2] - m_cur);
      const float p3 = exp2f(S[ct][3] - m_cur);
      rs += (p0 + p1) + (p2 + p3);
      pu[ct * 2 + 0] = (__float_as_uint(p1) & 0xffff0000u) | (__float_as_uint(p0) >> 16);
      pu[ct * 2 + 1] = (__float_as_uint(p3) & 0xffff0000u) | (__float_as_uint(p2) >> 16);
    }
    rs += __shfl_xor(rs, 16);
    rs += __shfl_xor(rs, 32);
    l_cur += rs;

    // in-register P transpose: lane (l15,quad) gets P^T[q=l15][k=8quad+m]
    bf16x8 bP[2];
    #pragma unroll
    for (int g = 0; g < 2; ++g) {
      const unsigned xA0 = (unsigned)__shfl((int)pu[4 * g + 0], sA);
      const unsigned yA0 = (unsigned)__shfl((int)pu[4 * g + 2], sA);
      const unsigned xA1 = (unsigned)__shfl((int)pu[4 * g + 1], sA);
      const unsigned yA1 = (unsigned)__shfl((int)pu[4 * g + 3], sA);
      const unsigned xB0 = (unsigned)__shfl((int)pu[4 * g + 0], sB);
      const unsigned yB0 = (unsigned)__shfl((int)pu[4 * g + 2], sB);
      const unsigned xB1 = (unsigned)__shfl((int)pu[4 * g + 1], sB);
      const unsigned yB1 = (unsigned)__shfl((int)pu[4 * g + 3], sB);
      union { unsigned u[4]; bf16x8 v; } cv;
      cv.u[0] = bsel ? yA0 : xA0;
      cv.u[1] = bsel ? yA1 : xA1;
      cv.u[2] = bsel ? yB0 : xB0;
      cv.u[3] = bsel ? yB1 : xB1;
      bP[g] = cv.v;
    }

    // ---- PV(tile j): O^T += V^T_frag x bP (V[j] staged last iter) ----
    {
      const unsigned short* VT = &VtS[j & 1][0];
      __builtin_amdgcn_s_setprio(1);
      #pragma unroll
      for (int g = 0; g < 2; ++g)
        #pragma unroll
        for (int n = 0; n < 8; ++n) {
          const bf16x8 av =
              *(const bf16x8*)&VT[g * 4096 + (n * 16 + l15) * 32 + ((quad ^ swz) << 3)];
          O[n] = mfma_bf16(av, bP[g], O[n]);
        }
      __builtin_amdgcn_s_setprio(0);
    }
  }

  // ---- epilogue: xo = x + O^T / l  (everything lane-local; float4 I/O) ----
  const int b = bh >> 3, hh = bh & 7;
  const float inv_l = 1.0f / l_cur;
  const int t = qt0 + w * 16 + l15;
  const size_t xrow = ((size_t)(b * T_ + t)) * C_ + (size_t)hh * DH;
  #pragma unroll
  for (int n = 0; n < 8; ++n) {
    const int d = n * 16 + quad * 4;
    const float4 xv = *(const float4*)(x + xrow + d);
    float4 ov;
    ov.x = xv.x + O[n][0] * inv_l;
    ov.y = xv.y + O[n][1] * inv_l;
    ov.z = xv.z + O[n][2] * inv_l;
    ov.w = xv.w + O[n][3] * inv_l;
    *(float4*)(xo + xrow + d) = ov;
  }
}

// ---------------------------------------------------------------------------
// Workspace layout (MB offsets):
//   0-32    xo    f32 [M][C]
//   32-48   q_hi  bf16 [bh][t][d] (pre-scaled)   \
//   48-64   q_lo  bf16 [bh][t][d]                 \
//   64-80   k_hi  bf16 image [bh][64][4][32][32]   } ff1 aliases 32-96 after attn
//   80-96   k_lo  bf16 image                      /
//   96-112  vimg  bf16 image [bh][64][128][32]
//   112-128 h_hi  bf16 [M][C]
//   128-144 h_lo  bf16 [M][C]
//   144-152 w1t   bf16 [DFF][C]
//   152-160 w2t   bf16 [C][DFF]
//   160-166 wt_hi bf16 [3H][DH][C]
//   166-172 wt_lo bf16 [3H][DH][C]
// ---------------------------------------------------------------------------
extern "C" void kernel_launch(void* const* d_in, const int* in_sizes, int n_in,
                              void* d_out, int out_size, void* d_ws, size_t ws_size,
                              hipStream_t stream) {
  (void)in_sizes; (void)n_in; (void)out_size; (void)ws_size;
  const float* x     = (const float*)d_in[0];
  const float* wq    = (const float*)d_in[1];
  const float* wk    = (const float*)d_in[2];
  const float* wv    = (const float*)d_in[3];
  const float* w1    = (const float*)d_in[4];
  const float* b1    = (const float*)d_in[5];
  const float* w2    = (const float*)d_in[6];
  const float* b2    = (const float*)d_in[7];
  const float* ln1_g = (const float*)d_in[8];
  const float* ln1_b = (const float*)d_in[9];
  const float* ln2_g = (const float*)d_in[10];
  const float* ln2_b = (const float*)d_in[11];
  float* out = (float*)d_out;

  char* W = (char*)d_ws;
  float* xo = (float*)(W);
  unsigned short* q_hi  = (unsigned short*)(W + (32u  << 20));
  unsigned short* q_lo  = (unsigned short*)(W + (48u  << 20));
  unsigned short* k_hi  = (unsigned short*)(W + (64u  << 20));
  unsigned short* k_lo  = (unsigned short*)(W + (80u  << 20));
  unsigned short* vimg  = (unsigned short*)(W + (96u  << 20));
  unsigned short* ff1   = (unsigned short*)(W + (32u  << 20));   // aliases q/k
  unsigned short* h_hi  = (unsigned short*)(W + (112u << 20));
  unsigned short* h_lo  = (unsigned short*)(W + (128u << 20));
  unsigned short* w1t   = (unsigned short*)(W + (144u << 20));
  unsigned short* w2t   = (unsigned short*)(W + (152u << 20));
  unsigned short* wt_hi = (unsigned short*)(W + (160u << 20));
  unsigned short* wt_lo = (unsigned short*)(W + (166u << 20));

  cvt_t_kernel<<<dim3(DFF / 32, C_ / 32), 256, 0, stream>>>(w1, w1t, C_, DFF);
  cvt_t_kernel<<<dim3(C_ / 32, DFF / 32), 256, 0, stream>>>(w2, w2t, DFF, C_);
  cvt_qkv_kernel<<<dim3(DH / 32, C_ / 32, 24), 256, 0, stream>>>(wq, wk, wv, wt_hi, wt_lo);
  ln_kernel<<<M_, 256, 0, stream>>>(x, ln1_g, ln1_b, h_hi, h_lo);
  qkm_kernel<<<dim3(M_ / 128, 16), 256, 0, stream>>>(h_hi, h_lo, wt_hi, wt_lo,
                                                     q_hi, q_lo, k_hi, k_lo);
  vm_kernel<<<dim3(M_ / 128, H_), 256, 0, stream>>>(h_hi, wt_hi, vimg);
  attn_kernel<<<dim3(T_ / BQ, B_ * H_), 512, 0, stream>>>(q_hi, q_lo, k_hi, k_lo,
                                                          vimg, x, xo);
  ln_kernel<<<M_, 256, 0, stream>>>(xo, ln2_g, ln2_b, h_hi, h_lo);
  ff1_kernel<<<dim3(DFF / 128, M_ / 128), 256, 0, stream>>>(h_hi, w1t, b1, ff1);
  ff2_kernel<<<dim3(C_ / 128, M_ / 128), 256, 0, stream>>>(ff1, w2t, b2, xo, out);
}

// Round 6
// 612.795 us; speedup vs baseline: 1.0720x; 1.0720x over previous
//
#include <hip/hip_runtime.h>
#include <hip/hip_bf16.h>
#include <math.h>

#define B_   4
#define T_   2048
#define C_   1024
#define H_   8
#define DH   128
#define DFF  4096
#define M_   (B_*T_)   // 8192 rows

typedef __attribute__((ext_vector_type(8))) short bf16x8;
typedef __attribute__((ext_vector_type(4))) float f32x4;
typedef __attribute__((ext_vector_type(2))) unsigned int u32x2;

// sqrt(128) * log2(e): scores computed directly in exp2 domain
#define SC2 16.32223094f

__device__ __forceinline__ unsigned short f2bf(float x) {
  union { float f; unsigned u; } v; v.f = x;
  return (unsigned short)((v.u + 0x7fffu + ((v.u >> 16) & 1u)) >> 16);
}
__device__ __forceinline__ float bf2f(unsigned short h) {
  union { unsigned u; float f; } v; v.u = ((unsigned)h) << 16; return v.f;
}

__device__ __forceinline__ f32x4 mfma_bf16(bf16x8 a, bf16x8 b, f32x4 c) {
  return __builtin_amdgcn_mfma_f32_16x16x32_bf16(a, b, c, 0, 0, 0);
}

// async global->LDS, 16B per lane; HW places lane i at wave-base + i*16
__device__ __forceinline__ void gll16(const void* g, void* l) {
  __builtin_amdgcn_global_load_lds((const __attribute__((address_space(1))) void*)g,
                                   (__attribute__((address_space(3))) void*)l,
                                   16, 0, 0);
}

// ---------------------------------------------------------------------------
// LayerNorm: one block per row, 256 threads; emits hi/lo split bf16.
// ---------------------------------------------------------------------------
__global__ __launch_bounds__(256) void ln_kernel(const float* __restrict__ in,
                                                 const float* __restrict__ g,
                                                 const float* __restrict__ bb,
                                                 unsigned short* __restrict__ h_hi,
                                                 unsigned short* __restrict__ h_lo) {
  __shared__ float red[8];
  const int row = blockIdx.x;
  const int tid = threadIdx.x;
  const float* p = in + (size_t)row * C_;
  const float4 xv = *(const float4*)(p + (tid << 2));
  float s  = xv.x + xv.y + xv.z + xv.w;
  float sq = xv.x*xv.x + xv.y*xv.y + xv.z*xv.z + xv.w*xv.w;
  #pragma unroll
  for (int off = 32; off > 0; off >>= 1) {
    s  += __shfl_xor(s, off);
    sq += __shfl_xor(sq, off);
  }
  if ((tid & 63) == 0) { red[(tid >> 6) * 2] = s; red[(tid >> 6) * 2 + 1] = sq; }
  __syncthreads();
  s  = red[0] + red[2] + red[4] + red[6];
  sq = red[1] + red[3] + red[5] + red[7];
  const float mu  = s * (1.0f / C_);
  const float var = sq * (1.0f / C_) - mu * mu;
  const float rs  = rsqrtf(var + 1e-5f);
  const float4 gv = *(const float4*)(g  + (tid << 2));
  const float4 bv = *(const float4*)(bb + (tid << 2));
  float ov[4];
  ov[0] = (xv.x - mu) * rs * gv.x + bv.x;
  ov[1] = (xv.y - mu) * rs * gv.y + bv.y;
  ov[2] = (xv.z - mu) * rs * gv.z + bv.z;
  ov[3] = (xv.w - mu) * rs * gv.w + bv.w;
  ushort4 hv, lv;
  unsigned short* hp = (unsigned short*)&hv;
  unsigned short* lp = (unsigned short*)&lv;
  #pragma unroll
  for (int j = 0; j < 4; ++j) {
    hp[j] = f2bf(ov[j]);
    lp[j] = f2bf(ov[j] - bf2f(hp[j]));
  }
  *(ushort4*)(h_hi + (size_t)row * C_ + (tid << 2)) = hv;
  *(ushort4*)(h_lo + (size_t)row * C_ + (tid << 2)) = lv;
}

// ---------------------------------------------------------------------------
// Weight converters (transpose to n-major k-contiguous bf16).
// ---------------------------------------------------------------------------
__global__ __launch_bounds__(256) void cvt_t_kernel(const float* __restrict__ in,
                                                    unsigned short* __restrict__ out,
                                                    int R, int CC) {
  __shared__ float tile[32][33];
  const int r0 = blockIdx.y << 5, c0 = blockIdx.x << 5;
  const int tr = threadIdx.x >> 3, tc4 = (threadIdx.x & 7) << 2;
  const float4 vv = *(const float4*)(in + (size_t)(r0 + tr) * CC + c0 + tc4);
  tile[tr][tc4+0] = vv.x; tile[tr][tc4+1] = vv.y;
  tile[tr][tc4+2] = vv.z; tile[tr][tc4+3] = vv.w;
  __syncthreads();
  ushort4 o;
  o.x = f2bf(tile[tc4+0][tr]); o.y = f2bf(tile[tc4+1][tr]);
  o.z = f2bf(tile[tc4+2][tr]); o.w = f2bf(tile[tc4+3][tr]);
  *(ushort4*)(out + (size_t)(c0 + tr) * R + r0 + tc4) = o;
}

// split hi/lo transpose for wq/wk/wv: in [H][C][DH] -> out[z][DH][C], z=which*8+h
__global__ __launch_bounds__(256) void cvt_qkv_kernel(const float* __restrict__ wq,
                                                      const float* __restrict__ wk,
                                                      const float* __restrict__ wv,
                                                      unsigned short* __restrict__ wt_hi,
                                                      unsigned short* __restrict__ wt_lo) {
  const int z = blockIdx.z;
  const int which = z >> 3, head = z & 7;
  const float* in = (which == 0 ? wq : (which == 1 ? wk : wv)) + (size_t)head * C_ * DH;
  unsigned short* oh = wt_hi + (size_t)z * DH * C_;
  unsigned short* ol = wt_lo + (size_t)z * DH * C_;
  __shared__ float tile[32][33];
  const int r0 = blockIdx.y << 5, c0 = blockIdx.x << 5;   // r over C, c over DH
  const int tr = threadIdx.x >> 3, tc4 = (threadIdx.x & 7) << 2;
  const float4 vv = *(const float4*)(in + (size_t)(r0 + tr) * DH + c0 + tc4);
  tile[tr][tc4+0] = vv.x; tile[tr][tc4+1] = vv.y;
  tile[tr][tc4+2] = vv.z; tile[tr][tc4+3] = vv.w;
  __syncthreads();
  ushort4 hv, lv;
  unsigned short* hp = (unsigned short*)&hv;
  unsigned short* lp = (unsigned short*)&lv;
  #pragma unroll
  for (int j = 0; j < 4; ++j) {
    const float val = tile[tc4+j][tr];
    hp[j] = f2bf(val);
    lp[j] = f2bf(val - bf2f(hp[j]));
  }
  *(ushort4*)(oh + (size_t)(c0 + tr) * C_ + r0 + tc4) = hv;
  *(ushort4*)(ol + (size_t)(c0 + tr) * C_ + r0 + tc4) = lv;
}

// ---------------------------------------------------------------------------
// LDS tile swizzle (all MFMA-staged tiles): rows are 64B (32 bf16 of k).
// LDS[r][c] = G[r][c ^ ((r>>1 & 3)<<3)], applied by swizzling the gll16
// GLOBAL source column (dest stays linear - global_load_lds requirement).
// ---------------------------------------------------------------------------

// ---------------------------------------------------------------------------
// Single-buffered split-precision GEMM (qkm only): 128x128 tile, BK=32,
// 4 waves. TERMS=3: Ah*Bh + Ah*Bl + Al*Bh.
// ---------------------------------------------------------------------------
__device__ __forceinline__ void gemm128_split3(
    const unsigned short* __restrict__ Ah, const unsigned short* __restrict__ Al,
    int lda,
    const unsigned short* __restrict__ Bh, const unsigned short* __restrict__ Bl,
    int ldb, int K, f32x4 (&acc)[4][4],
    unsigned short* AhS, unsigned short* AlS,
    unsigned short* BhS, unsigned short* BlS) {
  const int tid  = threadIdx.x;
  const int w    = tid >> 6;
  const int lane = tid & 63;
  const int l15  = lane & 15, quad = lane >> 4;
  const int srow = lane >> 2;
  const int skc  = ((lane & 3) << 3) ^ (((srow >> 1) & 3) << 3);  // pre-swizzled src col
  const int wm = w & 1, wn = w >> 1;
  const int ro = ((quad ^ ((l15 >> 1) & 3)) << 3);                // swizzled read col

  for (int k0 = 0; k0 < K; k0 += 32) {
    __syncthreads();
    #pragma unroll
    for (int i = 0; i < 2; ++i) {
      const int seg  = w * 2 + i;
      const int r    = seg * 16 + srow;
      const int lofs = seg * 512 + lane * 8;
      gll16(Ah + (size_t)r * lda + k0 + skc, AhS + lofs);
      gll16(Bh + (size_t)r * ldb + k0 + skc, BhS + lofs);
      gll16(Al + (size_t)r * lda + k0 + skc, AlS + lofs);
      gll16(Bl + (size_t)r * ldb + k0 + skc, BlS + lofs);
    }
    __syncthreads();
    bf16x8 aH[4], bH[4], aL[4], bL[4];
    #pragma unroll
    for (int t = 0; t < 4; ++t) {
      aH[t] = *(const bf16x8*)&AhS[(wm * 64 + t * 16 + l15) * 32 + ro];
      bH[t] = *(const bf16x8*)&BhS[(wn * 64 + t * 16 + l15) * 32 + ro];
      aL[t] = *(const bf16x8*)&AlS[(wm * 64 + t * 16 + l15) * 32 + ro];
      bL[t] = *(const bf16x8*)&BlS[(wn * 64 + t * 16 + l15) * 32 + ro];
    }
    #pragma unroll
    for (int rt = 0; rt < 4; ++rt)
      #pragma unroll
      for (int ct = 0; ct < 4; ++ct) {
        acc[rt][ct] = mfma_bf16(aL[rt], bH[ct], acc[rt][ct]);
        acc[rt][ct] = mfma_bf16(aH[rt], bL[ct], acc[rt][ct]);
        acc[rt][ct] = mfma_bf16(aH[rt], bH[ct], acc[rt][ct]);
      }
  }
}

// ---------------------------------------------------------------------------
// Double-buffered bf16 GEMM (vm/ff1/ff2): pipelined stage-after-barrier.
// ---------------------------------------------------------------------------
__device__ __forceinline__ void gemm128_db(
    const unsigned short* __restrict__ Ah, int lda,
    const unsigned short* __restrict__ Bh, int ldb, int K, f32x4 (&acc)[4][4],
    unsigned short (&AS0)[4096], unsigned short (&AS1)[4096],
    unsigned short (&BS0)[4096], unsigned short (&BS1)[4096]) {
  const int tid  = threadIdx.x;
  const int w    = tid >> 6;
  const int lane = tid & 63;
  const int l15  = lane & 15, quad = lane >> 4;
  const int srow = lane >> 2;
  const int skc  = ((lane & 3) << 3) ^ (((srow >> 1) & 3) << 3);
  const int wm = w & 1, wn = w >> 1;
  const int ro = ((quad ^ ((l15 >> 1) & 3)) << 3);
  const int Km = K - 1;

  auto STG = [&](int k0, unsigned short* A, unsigned short* B) {
    #pragma unroll
    for (int i = 0; i < 2; ++i) {
      const int seg  = w * 2 + i;
      const int r    = seg * 16 + srow;
      const int lofs = seg * 512 + lane * 8;
      gll16(Ah + (size_t)r * lda + k0 + skc, A + lofs);
      gll16(Bh + (size_t)r * ldb + k0 + skc, B + lofs);
    }
  };
  auto CMP = [&](const unsigned short* A, const unsigned short* B) {
    bf16x8 aH[4], bH[4];
    #pragma unroll
    for (int t = 0; t < 4; ++t) {
      aH[t] = *(const bf16x8*)&A[(wm * 64 + t * 16 + l15) * 32 + ro];
      bH[t] = *(const bf16x8*)&B[(wn * 64 + t * 16 + l15) * 32 + ro];
    }
    #pragma unroll
    for (int rt = 0; rt < 4; ++rt)
      #pragma unroll
      for (int ct = 0; ct < 4; ++ct)
        acc[rt][ct] = mfma_bf16(aH[rt], bH[ct], acc[rt][ct]);
  };

  STG(0, AS0, BS0);
  for (int k0 = 0; k0 < K; k0 += 64) {
    __syncthreads();
    STG((k0 + 32) & Km, AS1, BS1);
    CMP(AS0, BS0);
    __syncthreads();
    STG((k0 + 64) & Km, AS0, BS0);
    CMP(AS1, BS1);
  }
}

// ---------------------------------------------------------------------------
// QK projection (split precision). grid = (M/128=64, 2*H=16).
// which==0: q out [bh][t][d] bf16 hi/lo, PRE-SCALED by SC2 (exp2-domain).
// which==1: k out tile-image [bh][64 kt][4 kc][32 key][32 d-swz] bf16 hi/lo,
//           d column pre-swizzled: d' = d ^ ((key>>1 & 3)<<3).
// ---------------------------------------------------------------------------
__global__ __launch_bounds__(256) void qkm_kernel(const unsigned short* __restrict__ h_hi,
                                                  const unsigned short* __restrict__ h_lo,
                                                  const unsigned short* __restrict__ wt_hi,
                                                  const unsigned short* __restrict__ wt_lo,
                                                  unsigned short* __restrict__ q_hi,
                                                  unsigned short* __restrict__ q_lo,
                                                  unsigned short* __restrict__ k_hi,
                                                  unsigned short* __restrict__ k_lo) {
  __shared__ __align__(16) unsigned short AhS[4096], AlS[4096];
  __shared__ __align__(16) unsigned short BhS[4096], BlS[4096];
  const int m0 = blockIdx.x << 7;
  const int z  = blockIdx.y;
  const int which = z >> 3, head = z & 7;
  f32x4 acc[4][4];
  #pragma unroll
  for (int i = 0; i < 4; ++i)
    #pragma unroll
    for (int j = 0; j < 4; ++j)
      #pragma unroll
      for (int r = 0; r < 4; ++r) acc[i][j][r] = 0.f;
  gemm128_split3(h_hi + (size_t)m0 * C_, h_lo + (size_t)m0 * C_, C_,
                 wt_hi + (size_t)z * DH * C_, wt_lo + (size_t)z * DH * C_, C_,
                 C_, acc, AhS, AlS, BhS, BlS);
  const int lane = threadIdx.x & 63, w = threadIdx.x >> 6;
  const int l15 = lane & 15, quad = lane >> 4;
  const int wm = w & 1, wn = w >> 1;
  const int bh = (m0 >> 11) * H_ + head;
  const int tbase = (m0 & (T_ - 1)) + wm * 64 + quad * 4;
  if (which == 0) {
    #pragma unroll
    for (int rt = 0; rt < 4; ++rt)
      #pragma unroll
      for (int ct = 0; ct < 4; ++ct) {
        const int d = wn * 64 + ct * 16 + l15;
        #pragma unroll
        for (int r = 0; r < 4; ++r) {
          const int t = tbase + rt * 16 + r;
          const float val = acc[rt][ct][r] * SC2;
          const unsigned short hb = f2bf(val);
          const size_t idx = ((size_t)bh * T_ + t) * DH + d;
          q_hi[idx] = hb;
          q_lo[idx] = f2bf(val - bf2f(hb));
        }
      }
  } else {
    #pragma unroll
    for (int rt = 0; rt < 4; ++rt)
      #pragma unroll
      for (int ct = 0; ct < 4; ++ct) {
        const int d = wn * 64 + ct * 16 + l15;
        #pragma unroll
        for (int r = 0; r < 4; ++r) {
          const int t = tbase + rt * 16 + r;
          const int tt = t & 31;
          const float val = acc[rt][ct][r];
          const unsigned short hb = f2bf(val);
          const size_t idx = (((size_t)bh * 64 + (t >> 5)) * 4 + (d >> 5)) * 1024
                           + (size_t)tt * 32 + ((d & 31) ^ (((tt >> 1) & 3) << 3));
          k_hi[idx] = hb;
          k_lo[idx] = f2bf(val - bf2f(hb));
        }
      }
  }
}

// ---------------------------------------------------------------------------
// V projection (plain bf16). grid = (M/128=64, H=8).
// v out tile-image [bh][64 kt][128 d][32 key-swz], key' = key ^ ((d>>1 &3)<<3).
// ---------------------------------------------------------------------------
__global__ __launch_bounds__(256) void vm_kernel(const unsigned short* __restrict__ h_hi,
                                                 const unsigned short* __restrict__ wv_hi,
                                                 unsigned short* __restrict__ vimg) {
  __shared__ __align__(16) unsigned short AS0[4096], AS1[4096];
  __shared__ __align__(16) unsigned short BS0[4096], BS1[4096];
  const int m0 = blockIdx.x << 7;
  const int head = blockIdx.y;
  f32x4 acc[4][4];
  #pragma unroll
  for (int i = 0; i < 4; ++i)
    #pragma unroll
    for (int j = 0; j < 4; ++j)
      #pragma unroll
      for (int r = 0; r < 4; ++r) acc[i][j][r] = 0.f;
  gemm128_db(h_hi + (size_t)m0 * C_, C_,
             wv_hi + (size_t)(16 + head) * DH * C_, C_,
             C_, acc, AS0, AS1, BS0, BS1);
  const int lane = threadIdx.x & 63, w = threadIdx.x >> 6;
  const int l15 = lane & 15, quad = lane >> 4;
  const int wm = w & 1, wn = w >> 1;
  const int bh = (m0 >> 11) * H_ + head;
  #pragma unroll
  for (int rt = 0; rt < 4; ++rt)
    #pragma unroll
    for (int ct = 0; ct < 4; ++ct) {
      const int d  = wn * 64 + ct * 16 + l15;
      const int t0 = (m0 & (T_ - 1)) + wm * 64 + rt * 16 + quad * 4;
      const int key = (t0 & 31) ^ (((d >> 1) & 3) << 3);
      ushort4 pk;
      pk.x = f2bf(acc[rt][ct][0]); pk.y = f2bf(acc[rt][ct][1]);
      pk.z = f2bf(acc[rt][ct][2]); pk.w = f2bf(acc[rt][ct][3]);
      *(ushort4*)&vimg[(((size_t)bh * 64 + (t0 >> 5)) * 128 + d) * 32 + key] = pk;
    }
}

// ---------------------------------------------------------------------------
// FF1: ff1 = bf16(relu(h2 @ w1 + b1)).  grid = (DFF/128=32, M/128=64)
// ---------------------------------------------------------------------------
__global__ __launch_bounds__(256) void ff1_kernel(const unsigned short* __restrict__ h2,
                                                  const unsigned short* __restrict__ w1t,
                                                  const float* __restrict__ b1,
                                                  unsigned short* __restrict__ ff1) {
  __shared__ __align__(16) unsigned short AS0[4096], AS1[4096];
  __shared__ __align__(16) unsigned short BS0[4096], BS1[4096];
  const int n0 = blockIdx.x << 7;
  const int m0 = blockIdx.y << 7;
  f32x4 acc[4][4];
  #pragma unroll
  for (int i = 0; i < 4; ++i)
    #pragma unroll
    for (int j = 0; j < 4; ++j)
      #pragma unroll
      for (int r = 0; r < 4; ++r) acc[i][j][r] = 0.f;
  gemm128_db(h2 + (size_t)m0 * C_, C_,
             w1t + (size_t)n0 * C_, C_,
             C_, acc, AS0, AS1, BS0, BS1);
  const int lane = threadIdx.x & 63, w = threadIdx.x >> 6;
  const int l15 = lane & 15, quad = lane >> 4;
  const int wm = w & 1, wn = w >> 1;
  #pragma unroll
  for (int rt = 0; rt < 4; ++rt)
    #pragma unroll
    for (int ct = 0; ct < 4; ++ct) {
      const int n = n0 + wn * 64 + ct * 16 + l15;
      const float bias = b1[n];
      #pragma unroll
      for (int r = 0; r < 4; ++r) {
        const int m = m0 + wm * 64 + rt * 16 + quad * 4 + r;
        ff1[(size_t)m * DFF + n] = f2bf(fmaxf(acc[rt][ct][r] + bias, 0.f));
      }
    }
}

// ---------------------------------------------------------------------------
// FF2: out = ff1 @ w2 + b2 + xo.  grid = (C/128=8, M/128=64)
// ---------------------------------------------------------------------------
__global__ __launch_bounds__(256) void ff2_kernel(const unsigned short* __restrict__ ff1,
                                                  const unsigned short* __restrict__ w2t,
                                                  const float* __restrict__ b2,
                                                  const float* __restrict__ xo,
                                                  float* __restrict__ out) {
  __shared__ __align__(16) unsigned short AS0[4096], AS1[4096];
  __shared__ __align__(16) unsigned short BS0[4096], BS1[4096];
  const int n0 = blockIdx.x << 7;
  const int m0 = blockIdx.y << 7;
  f32x4 acc[4][4];
  #pragma unroll
  for (int i = 0; i < 4; ++i)
    #pragma unroll
    for (int j = 0; j < 4; ++j)
      #pragma unroll
      for (int r = 0; r < 4; ++r) acc[i][j][r] = 0.f;
  gemm128_db(ff1 + (size_t)m0 * DFF, DFF,
             w2t + (size_t)n0 * DFF, DFF,
             DFF, acc, AS0, AS1, BS0, BS1);
  const int lane = threadIdx.x & 63, w = threadIdx.x >> 6;
  const int l15 = lane & 15, quad = lane >> 4;
  const int wm = w & 1, wn = w >> 1;
  #pragma unroll
  for (int rt = 0; rt < 4; ++rt)
    #pragma unroll
    for (int ct = 0; ct < 4; ++ct) {
      const int n = n0 + wn * 64 + ct * 16 + l15;
      const float bias = b2[n];
      #pragma unroll
      for (int r = 0; r < 4; ++r) {
        const int m = m0 + wm * 64 + rt * 16 + quad * 4 + r;
        out[(size_t)m * C_ + n] = acc[rt][ct][r] + bias + xo[(size_t)m * C_ + n];
      }
    }
}

// ---------------------------------------------------------------------------
// MFMA flash attention, v6: 32 q-rows PER WAVE (LDS-BW amortization).
// Theory: attn is LDS-read-BW-bound — every wave reads the full K/V tile
// regardless of q-count, so fat waves halve LDS bytes per unit work.
// 8 waves x 32 q = BQ 256; grid (T/256=8, B*H=32) = 256 blocks = 1/CU.
// K/V fragment reads are shared across both rt q-groups (read once, 2 rt
// MFMAs). Schedule = R3-v3's proven covered 3-barrier pattern. LDS 64KB.
// O^T accumulation (lane-local stats), in-reg P transpose, defer-max.
// ---------------------------------------------------------------------------
#define BQ 256

__global__ __launch_bounds__(512, 2) void attn_kernel(
    const unsigned short* __restrict__ q_hi, const unsigned short* __restrict__ q_lo,
    const unsigned short* __restrict__ k_hi, const unsigned short* __restrict__ k_lo,
    const unsigned short* __restrict__ vimg,
    const float* __restrict__ x, float* __restrict__ xo) {
  __shared__ __align__(16) unsigned short Kh0[4096], Kh1[4096];   // 32-key K tiles
  __shared__ __align__(16) unsigned short Kl0[4096], Kl1[4096];
  __shared__ __align__(16) unsigned short Vt0[8192], Vt1[8192];   // 64-key V tiles

  // XCD-aware remap (bijective, 256 blocks = 8 XCD x 32)
  const int bid   = blockIdx.x + (T_ / BQ) * blockIdx.y;
  const int chunk = bid >> 3;                 // 0..31
  const int bh    = (bid & 7) * 4 + (chunk >> 3);
  const int qt0   = (chunk & 7) * BQ;

  const int tid  = threadIdx.x;
  const int w    = tid >> 6;           // 0..7
  const int lane = tid & 63;
  const int l15  = lane & 15;
  const int quad = lane >> 4;
  const int swz  = (l15 >> 1) & 3;     // LDS row-dependent slot swizzle key
  // P-transpose shuffle sources (same l15, cross-quad)
  const int sA   = ((quad & 1) << 5) + l15;   // quad_s = (quad&1)*2
  const int sB   = sA + 16;                   // quad_s = (quad&1)*2 + 1
  const int bsel = (quad >> 1) & 1;           // ct-parity select

  // ---- Q fragments (pre-scaled hi/lo bf16), 32 rows per wave (2 rt) ----
  bf16x8 Qh[2][4], Ql[2][4];
  #pragma unroll
  for (int rt = 0; rt < 2; ++rt) {
    const int row = qt0 + w * 32 + rt * 16 + l15;
    #pragma unroll
    for (int kc = 0; kc < 4; ++kc) {
      const size_t off = ((size_t)bh * T_ + row) * DH + kc * 32 + quad * 8;
      Qh[rt][kc] = *(const bf16x8*)(q_hi + off);
      Ql[rt][kc] = *(const bf16x8*)(q_lo + off);
    }
  }

  f32x4 O[2][8];   // O^T: lane holds O^T[d=16n+4quad+r][q=rt*16+l15]
  #pragma unroll
  for (int rt = 0; rt < 2; ++rt)
    #pragma unroll
    for (int n = 0; n < 8; ++n)
      #pragma unroll
      for (int r = 0; r < 4; ++r) O[rt][n][r] = 0.f;
  float m_cur[2] = { -1e30f, -1e30f };   // running max for q=rt*16+l15 (log2)
  float l_cur[2] = { 0.f, 0.f };

  auto STAGE_K = [&](int kt, unsigned short* KH, unsigned short* KL) {
    const size_t tb = ((size_t)bh * 64 + (kt & 63)) * 4096;
    const int o = tid * 8;
    gll16(k_hi + tb + o, KH + o);
    gll16(k_lo + tb + o, KL + o);
  };
  auto STAGE_V = [&](int jv, unsigned short* VT) {
    const size_t tb = ((size_t)bh * 64 + (jv & 31) * 2) * 4096;
    const int o = tid * 8;
    gll16(vimg + tb + o, VT + o);
    gll16(vimg + tb + 4096 + o, VT + 4096 + o);
  };
  // 32-key QK^T serving BOTH rt groups from one K-fragment read.
  auto QKT = [&](const unsigned short* KH, const unsigned short* KL,
                 f32x4 (&S2)[2][2]) {
    __builtin_amdgcn_s_setprio(1);
    #pragma unroll
    for (int kc = 0; kc < 4; ++kc)
      #pragma unroll
      for (int c2 = 0; c2 < 2; ++c2) {
        const int o = kc * 1024 + (c2 * 16 + l15) * 32 + ((quad ^ swz) << 3);
        const bf16x8 kh = *(const bf16x8*)&KH[o];
        const bf16x8 kl = *(const bf16x8*)&KL[o];
        #pragma unroll
        for (int rt = 0; rt < 2; ++rt) {
          S2[c2][rt] = mfma_bf16(kl, Qh[rt][kc], S2[c2][rt]);
          S2[c2][rt] = mfma_bf16(kh, Ql[rt][kc], S2[c2][rt]);
          S2[c2][rt] = mfma_bf16(kh, Qh[rt][kc], S2[c2][rt]);
        }
      }
    __builtin_amdgcn_s_setprio(0);
  };

  STAGE_K(0, Kh0, Kl0);
  STAGE_K(1, Kh1, Kl1);
  STAGE_V(0, Vt0);

  for (int j = 0; j < T_ / 64; ++j) {          // 32 iters, 64 keys each
    __syncthreads();                           // B1: drains prev-iter tail stage
    // S[ct][rt]: row=key=ct*16+4quad+r, col=q=rt*16+l15
    f32x4 S[4][2];
    #pragma unroll
    for (int ct = 0; ct < 4; ++ct)
      #pragma unroll
      for (int rt = 0; rt < 2; ++rt)
        #pragma unroll
        for (int r = 0; r < 4; ++r) S[ct][rt][r] = 0.f;

    QKT(Kh0, Kl0, *(f32x4 (*)[2][2])&S[0]);    // keys 0..31
    __syncthreads();                           // B2: all waves done reading K0
    STAGE_K(2 * j + 2, Kh0, Kl0);              // lands under QKT(K1)..next B1
    STAGE_V(j + 1, (j & 1) ? Vt0 : Vt1);
    QKT(Kh1, Kl1, *(f32x4 (*)[2][2])&S[2]);    // keys 32..63
    __syncthreads();                           // B3: done with K1; covers stages
    STAGE_K(2 * j + 3, Kh1, Kl1);              // lands under softmax+PV+B1

    // ---- softmax over 64 keys, both rt (lane-local stats at q=rt*16+l15) ----
    float mx[2];
    #pragma unroll
    for (int rt = 0; rt < 2; ++rt) {
      float m0 = -1e30f;
      #pragma unroll
      for (int ct = 0; ct < 4; ++ct)
        m0 = fmaxf(m0, fmaxf(fmaxf(S[ct][rt][0], S[ct][rt][1]),
                             fmaxf(S[ct][rt][2], S[ct][rt][3])));
      m0 = fmaxf(m0, __shfl_xor(m0, 16));
      m0 = fmaxf(m0, __shfl_xor(m0, 32));
      mx[rt] = m0;
    }
    const int need = (mx[0] > m_cur[0] + 8.f) || (mx[1] > m_cur[1] + 8.f);
    if (__any(need)) {
      #pragma unroll
      for (int rt = 0; rt < 2; ++rt) {
        const float mn = fmaxf(m_cur[rt], mx[rt]);
        const float al = exp2f(m_cur[rt] - mn);
        m_cur[rt] = mn;
        l_cur[rt] *= al;
        #pragma unroll
        for (int n = 0; n < 8; ++n)
          #pragma unroll
          for (int r = 0; r < 4; ++r) O[rt][n][r] *= al;
      }
    }

    // P = exp2(S - m), truncation-pack; in-reg transpose -> bP[rt][g]
    bf16x8 bP[2][2];
    #pragma unroll
    for (int rt = 0; rt < 2; ++rt) {
      unsigned pu[8];
      float rs = 0.f;
      #pragma unroll
      for (int ct = 0; ct < 4; ++ct) {
        const float p0 = exp2f(S[ct][rt][0] - m_cur[rt]);
        const float p1 = exp2f(S[ct][rt][1] - m_cur[rt]);
        const float p2 = exp2f(S[ct][rt][2] - m_cur[rt]);
        const float p3 = exp2f(S[ct][rt][3] - m_cur[rt]);
        rs += (p0 + p1) + (p2 + p3);
        pu[ct * 2 + 0] = (__float_as_uint(p1) & 0xffff0000u) | (__float_as_uint(p0) >> 16);
        pu[ct * 2 + 1] = (__float_as_uint(p3) & 0xffff0000u) | (__float_as_uint(p2) >> 16);
      }
      rs += __shfl_xor(rs, 16);
      rs += __shfl_xor(rs, 32);
      l_cur[rt] += rs;
      #pragma unroll
      for (int g = 0; g < 2; ++g) {
        const unsigned xA0 = (unsigned)__shfl((int)pu[4 * g + 0], sA);
        const unsigned yA0 = (unsigned)__shfl((int)pu[4 * g + 2], sA);
        const unsigned xA1 = (unsigned)__shfl((int)pu[4 * g + 1], sA);
        const unsigned yA1 = (unsigned)__shfl((int)pu[4 * g + 3], sA);
        const unsigned xB0 = (unsigned)__shfl((int)pu[4 * g + 0], sB);
        const unsigned yB0 = (unsigned)__shfl((int)pu[4 * g + 2], sB);
        const unsigned xB1 = (unsigned)__shfl((int)pu[4 * g + 1], sB);
        const unsigned yB1 = (unsigned)__shfl((int)pu[4 * g + 3], sB);
        union { unsigned u[4]; bf16x8 v; } cv;
        cv.u[0] = bsel ? yA0 : xA0;
        cv.u[1] = bsel ? yA1 : xA1;
        cv.u[2] = bsel ? yB0 : xB0;
        cv.u[3] = bsel ? yB1 : xB1;
        bP[rt][g] = cv.v;
      }
    }

    // ---- PV: O^T[rt] += V^T_frag x bP[rt]; V-frag read ONCE serves both rt ----
    {
      const unsigned short* VT = (j & 1) ? Vt1 : Vt0;
      __builtin_amdgcn_s_setprio(1);
      #pragma unroll
      for (int g = 0; g < 2; ++g)
        #pragma unroll
        for (int n = 0; n < 8; ++n) {
          const bf16x8 av =
              *(const bf16x8*)&VT[g * 4096 + (n * 16 + l15) * 32 + ((quad ^ swz) << 3)];
          O[0][n] = mfma_bf16(av, bP[0][g], O[0][n]);
          O[1][n] = mfma_bf16(av, bP[1][g], O[1][n]);
        }
      __builtin_amdgcn_s_setprio(0);
    }
  }

  // ---- epilogue: xo = x + O^T / l  (lane-local; float4 I/O) ----
  const int b = bh >> 3, hh = bh & 7;
  #pragma unroll
  for (int rt = 0; rt < 2; ++rt) {
    const float inv_l = 1.0f / l_cur[rt];
    const int t = qt0 + w * 32 + rt * 16 + l15;
    const size_t xrow = ((size_t)(b * T_ + t)) * C_ + (size_t)hh * DH;
    #pragma unroll
    for (int n = 0; n < 8; ++n) {
      const int d = n * 16 + quad * 4;
      const float4 xv = *(const float4*)(x + xrow + d);
      float4 ov;
      ov.x = xv.x + O[rt][n][0] * inv_l;
      ov.y = xv.y + O[rt][n][1] * inv_l;
      ov.z = xv.z + O[rt][n][2] * inv_l;
      ov.w = xv.w + O[rt][n][3] * inv_l;
      *(float4*)(xo + xrow + d) = ov;
    }
  }
}

// ---------------------------------------------------------------------------
// Workspace layout (MB offsets):
//   0-32    xo    f32 [M][C]
//   32-48   q_hi  bf16 [bh][t][d] (pre-scaled)   \
//   48-64   q_lo  bf16 [bh][t][d]                 \
//   64-80   k_hi  bf16 image [bh][64][4][32][32]   } ff1 aliases 32-96 after attn
//   80-96   k_lo  bf16 image                      /
//   96-112  vimg  bf16 image [bh][64][128][32]
//   112-128 h_hi  bf16 [M][C]
//   128-144 h_lo  bf16 [M][C]
//   144-152 w1t   bf16 [DFF][C]
//   152-160 w2t   bf16 [C][DFF]
//   160-166 wt_hi bf16 [3H][DH][C]
//   166-172 wt_lo bf16 [3H][DH][C]
// ---------------------------------------------------------------------------
extern "C" void kernel_launch(void* const* d_in, const int* in_sizes, int n_in,
                              void* d_out, int out_size, void* d_ws, size_t ws_size,
                              hipStream_t stream) {
  (void)in_sizes; (void)n_in; (void)out_size; (void)ws_size;
  const float* x     = (const float*)d_in[0];
  const float* wq    = (const float*)d_in[1];
  const float* wk    = (const float*)d_in[2];
  const float* wv    = (const float*)d_in[3];
  const float* w1    = (const float*)d_in[4];
  const float* b1    = (const float*)d_in[5];
  const float* w2    = (const float*)d_in[6];
  const float* b2    = (const float*)d_in[7];
  const float* ln1_g = (const float*)d_in[8];
  const float* ln1_b = (const float*)d_in[9];
  const float* ln2_g = (const float*)d_in[10];
  const float* ln2_b = (const float*)d_in[11];
  float* out = (float*)d_out;

  char* W = (char*)d_ws;
  float* xo = (float*)(W);
  unsigned short* q_hi  = (unsigned short*)(W + (32u  << 20));
  unsigned short* q_lo  = (unsigned short*)(W + (48u  << 20));
  unsigned short* k_hi  = (unsigned short*)(W + (64u  << 20));
  unsigned short* k_lo  = (unsigned short*)(W + (80u  << 20));
  unsigned short* vimg  = (unsigned short*)(W + (96u  << 20));
  unsigned short* ff1   = (unsigned short*)(W + (32u  << 20));   // aliases q/k
  unsigned short* h_hi  = (unsigned short*)(W + (112u << 20));
  unsigned short* h_lo  = (unsigned short*)(W + (128u << 20));
  unsigned short* w1t   = (unsigned short*)(W + (144u << 20));
  unsigned short* w2t   = (unsigned short*)(W + (152u << 20));
  unsigned short* wt_hi = (unsigned short*)(W + (160u << 20));
  unsigned short* wt_lo = (unsigned short*)(W + (166u << 20));

  cvt_t_kernel<<<dim3(DFF / 32, C_ / 32), 256, 0, stream>>>(w1, w1t, C_, DFF);
  cvt_t_kernel<<<dim3(C_ / 32, DFF / 32), 256, 0, stream>>>(w2, w2t, DFF, C_);
  cvt_qkv_kernel<<<dim3(DH / 32, C_ / 32, 24), 256, 0, stream>>>(wq, wk, wv, wt_hi, wt_lo);
  ln_kernel<<<M_, 256, 0, stream>>>(x, ln1_g, ln1_b, h_hi, h_lo);
  qkm_kernel<<<dim3(M_ / 128, 16), 256, 0, stream>>>(h_hi, h_lo, wt_hi, wt_lo,
                                                     q_hi, q_lo, k_hi, k_lo);
  vm_kernel<<<dim3(M_ / 128, H_), 256, 0, stream>>>(h_hi, wt_hi, vimg);
  attn_kernel<<<dim3(T_ / BQ, B_ * H_), 512, 0, stream>>>(q_hi, q_lo, k_hi, k_lo,
                                                          vimg, x, xo);
  ln_kernel<<<M_, 256, 0, stream>>>(xo, ln2_g, ln2_b, h_hi, h_lo);
  ff1_kernel<<<dim3(DFF / 128, M_ / 128), 256, 0, stream>>>(h_hi, w1t, b1, ff1);
  ff2_kernel<<<dim3(C_ / 128, M_ / 128), 256, 0, stream>>>(ff1, w2t, b2, xo, out);
}

// Round 7
// 599.190 us; speedup vs baseline: 1.0963x; 1.0227x over previous
//
#include <hip/hip_runtime.h>
#include <hip/hip_bf16.h>
#include <math.h>

#define B_   4
#define T_   2048
#define C_   1024
#define H_   8
#define DH   128
#define DFF  4096
#define M_   (B_*T_)   // 8192 rows

typedef __attribute__((ext_vector_type(8))) short bf16x8;
typedef __attribute__((ext_vector_type(4))) float f32x4;
typedef __attribute__((ext_vector_type(2))) unsigned int u32x2;

// sqrt(128) * log2(e): scores computed directly in exp2 domain
#define SC2 16.32223094f

__device__ __forceinline__ unsigned short f2bf(float x) {
  union { float f; unsigned u; } v; v.f = x;
  return (unsigned short)((v.u + 0x7fffu + ((v.u >> 16) & 1u)) >> 16);
}
__device__ __forceinline__ float bf2f(unsigned short h) {
  union { unsigned u; float f; } v; v.u = ((unsigned)h) << 16; return v.f;
}

__device__ __forceinline__ f32x4 mfma_bf16(bf16x8 a, bf16x8 b, f32x4 c) {
  return __builtin_amdgcn_mfma_f32_16x16x32_bf16(a, b, c, 0, 0, 0);
}

// async global->LDS, 16B per lane; HW places lane i at wave-base + i*16
__device__ __forceinline__ void gll16(const void* g, void* l) {
  __builtin_amdgcn_global_load_lds((const __attribute__((address_space(1))) void*)g,
                                   (__attribute__((address_space(3))) void*)l,
                                   16, 0, 0);
}

// ---------------------------------------------------------------------------
// LayerNorm: one block per row, 256 threads; emits hi/lo split bf16.
// ---------------------------------------------------------------------------
__global__ __launch_bounds__(256) void ln_kernel(const float* __restrict__ in,
                                                 const float* __restrict__ g,
                                                 const float* __restrict__ bb,
                                                 unsigned short* __restrict__ h_hi,
                                                 unsigned short* __restrict__ h_lo) {
  __shared__ float red[8];
  const int row = blockIdx.x;
  const int tid = threadIdx.x;
  const float* p = in + (size_t)row * C_;
  const float4 xv = *(const float4*)(p + (tid << 2));
  float s  = xv.x + xv.y + xv.z + xv.w;
  float sq = xv.x*xv.x + xv.y*xv.y + xv.z*xv.z + xv.w*xv.w;
  #pragma unroll
  for (int off = 32; off > 0; off >>= 1) {
    s  += __shfl_xor(s, off);
    sq += __shfl_xor(sq, off);
  }
  if ((tid & 63) == 0) { red[(tid >> 6) * 2] = s; red[(tid >> 6) * 2 + 1] = sq; }
  __syncthreads();
  s  = red[0] + red[2] + red[4] + red[6];
  sq = red[1] + red[3] + red[5] + red[7];
  const float mu  = s * (1.0f / C_);
  const float var = sq * (1.0f / C_) - mu * mu;
  const float rs  = rsqrtf(var + 1e-5f);
  const float4 gv = *(const float4*)(g  + (tid << 2));
  const float4 bv = *(const float4*)(bb + (tid << 2));
  float ov[4];
  ov[0] = (xv.x - mu) * rs * gv.x + bv.x;
  ov[1] = (xv.y - mu) * rs * gv.y + bv.y;
  ov[2] = (xv.z - mu) * rs * gv.z + bv.z;
  ov[3] = (xv.w - mu) * rs * gv.w + bv.w;
  ushort4 hv, lv;
  unsigned short* hp = (unsigned short*)&hv;
  unsigned short* lp = (unsigned short*)&lv;
  #pragma unroll
  for (int j = 0; j < 4; ++j) {
    hp[j] = f2bf(ov[j]);
    lp[j] = f2bf(ov[j] - bf2f(hp[j]));
  }
  *(ushort4*)(h_hi + (size_t)row * C_ + (tid << 2)) = hv;
  *(ushort4*)(h_lo + (size_t)row * C_ + (tid << 2)) = lv;
}

// ---------------------------------------------------------------------------
// Weight converters (transpose to n-major k-contiguous bf16).
// ---------------------------------------------------------------------------
__global__ __launch_bounds__(256) void cvt_t_kernel(const float* __restrict__ in,
                                                    unsigned short* __restrict__ out,
                                                    int R, int CC) {
  __shared__ float tile[32][33];
  const int r0 = blockIdx.y << 5, c0 = blockIdx.x << 5;
  const int tr = threadIdx.x >> 3, tc4 = (threadIdx.x & 7) << 2;
  const float4 vv = *(const float4*)(in + (size_t)(r0 + tr) * CC + c0 + tc4);
  tile[tr][tc4+0] = vv.x; tile[tr][tc4+1] = vv.y;
  tile[tr][tc4+2] = vv.z; tile[tr][tc4+3] = vv.w;
  __syncthreads();
  ushort4 o;
  o.x = f2bf(tile[tc4+0][tr]); o.y = f2bf(tile[tc4+1][tr]);
  o.z = f2bf(tile[tc4+2][tr]); o.w = f2bf(tile[tc4+3][tr]);
  *(ushort4*)(out + (size_t)(c0 + tr) * R + r0 + tc4) = o;
}

// split hi/lo transpose for wq/wk/wv: in [H][C][DH] -> out[z][DH][C], z=which*8+h
__global__ __launch_bounds__(256) void cvt_qkv_kernel(const float* __restrict__ wq,
                                                      const float* __restrict__ wk,
                                                      const float* __restrict__ wv,
                                                      unsigned short* __restrict__ wt_hi,
                                                      unsigned short* __restrict__ wt_lo) {
  const int z = blockIdx.z;
  const int which = z >> 3, head = z & 7;
  const float* in = (which == 0 ? wq : (which == 1 ? wk : wv)) + (size_t)head * C_ * DH;
  unsigned short* oh = wt_hi + (size_t)z * DH * C_;
  unsigned short* ol = wt_lo + (size_t)z * DH * C_;
  __shared__ float tile[32][33];
  const int r0 = blockIdx.y << 5, c0 = blockIdx.x << 5;   // r over C, c over DH
  const int tr = threadIdx.x >> 3, tc4 = (threadIdx.x & 7) << 2;
  const float4 vv = *(const float4*)(in + (size_t)(r0 + tr) * DH + c0 + tc4);
  tile[tr][tc4+0] = vv.x; tile[tr][tc4+1] = vv.y;
  tile[tr][tc4+2] = vv.z; tile[tr][tc4+3] = vv.w;
  __syncthreads();
  ushort4 hv, lv;
  unsigned short* hp = (unsigned short*)&hv;
  unsigned short* lp = (unsigned short*)&lv;
  #pragma unroll
  for (int j = 0; j < 4; ++j) {
    const float val = tile[tc4+j][tr];
    hp[j] = f2bf(val);
    lp[j] = f2bf(val - bf2f(hp[j]));
  }
  *(ushort4*)(oh + (size_t)(c0 + tr) * C_ + r0 + tc4) = hv;
  *(ushort4*)(ol + (size_t)(c0 + tr) * C_ + r0 + tc4) = lv;
}

// ---------------------------------------------------------------------------
// LDS tile swizzle (all MFMA-staged tiles): rows are 64B (32 bf16 of k).
// LDS[r][c] = G[r][c ^ ((r>>1 & 3)<<3)], applied by swizzling the gll16
// GLOBAL source column (dest stays linear - global_load_lds requirement).
// ---------------------------------------------------------------------------

// ---------------------------------------------------------------------------
// Single-buffered split-precision GEMM (qkm only): 128x128 tile, BK=32,
// 4 waves. TERMS=3: Ah*Bh + Ah*Bl + Al*Bh.
// ---------------------------------------------------------------------------
__device__ __forceinline__ void gemm128_split3(
    const unsigned short* __restrict__ Ah, const unsigned short* __restrict__ Al,
    int lda,
    const unsigned short* __restrict__ Bh, const unsigned short* __restrict__ Bl,
    int ldb, int K, f32x4 (&acc)[4][4],
    unsigned short* AhS, unsigned short* AlS,
    unsigned short* BhS, unsigned short* BlS) {
  const int tid  = threadIdx.x;
  const int w    = tid >> 6;
  const int lane = tid & 63;
  const int l15  = lane & 15, quad = lane >> 4;
  const int srow = lane >> 2;
  const int skc  = ((lane & 3) << 3) ^ (((srow >> 1) & 3) << 3);  // pre-swizzled src col
  const int wm = w & 1, wn = w >> 1;
  const int ro = ((quad ^ ((l15 >> 1) & 3)) << 3);                // swizzled read col

  for (int k0 = 0; k0 < K; k0 += 32) {
    __syncthreads();
    #pragma unroll
    for (int i = 0; i < 2; ++i) {
      const int seg  = w * 2 + i;
      const int r    = seg * 16 + srow;
      const int lofs = seg * 512 + lane * 8;
      gll16(Ah + (size_t)r * lda + k0 + skc, AhS + lofs);
      gll16(Bh + (size_t)r * ldb + k0 + skc, BhS + lofs);
      gll16(Al + (size_t)r * lda + k0 + skc, AlS + lofs);
      gll16(Bl + (size_t)r * ldb + k0 + skc, BlS + lofs);
    }
    __syncthreads();
    bf16x8 aH[4], bH[4], aL[4], bL[4];
    #pragma unroll
    for (int t = 0; t < 4; ++t) {
      aH[t] = *(const bf16x8*)&AhS[(wm * 64 + t * 16 + l15) * 32 + ro];
      bH[t] = *(const bf16x8*)&BhS[(wn * 64 + t * 16 + l15) * 32 + ro];
      aL[t] = *(const bf16x8*)&AlS[(wm * 64 + t * 16 + l15) * 32 + ro];
      bL[t] = *(const bf16x8*)&BlS[(wn * 64 + t * 16 + l15) * 32 + ro];
    }
    #pragma unroll
    for (int rt = 0; rt < 4; ++rt)
      #pragma unroll
      for (int ct = 0; ct < 4; ++ct) {
        acc[rt][ct] = mfma_bf16(aL[rt], bH[ct], acc[rt][ct]);
        acc[rt][ct] = mfma_bf16(aH[rt], bL[ct], acc[rt][ct]);
        acc[rt][ct] = mfma_bf16(aH[rt], bH[ct], acc[rt][ct]);
      }
  }
}

// ---------------------------------------------------------------------------
// Double-buffered bf16 GEMM (vm/ff1/ff2): pipelined stage-after-barrier.
// ---------------------------------------------------------------------------
__device__ __forceinline__ void gemm128_db(
    const unsigned short* __restrict__ Ah, int lda,
    const unsigned short* __restrict__ Bh, int ldb, int K, f32x4 (&acc)[4][4],
    unsigned short (&AS0)[4096], unsigned short (&AS1)[4096],
    unsigned short (&BS0)[4096], unsigned short (&BS1)[4096]) {
  const int tid  = threadIdx.x;
  const int w    = tid >> 6;
  const int lane = tid & 63;
  const int l15  = lane & 15, quad = lane >> 4;
  const int srow = lane >> 2;
  const int skc  = ((lane & 3) << 3) ^ (((srow >> 1) & 3) << 3);
  const int wm = w & 1, wn = w >> 1;
  const int ro = ((quad ^ ((l15 >> 1) & 3)) << 3);
  const int Km = K - 1;

  auto STG = [&](int k0, unsigned short* A, unsigned short* B) {
    #pragma unroll
    for (int i = 0; i < 2; ++i) {
      const int seg  = w * 2 + i;
      const int r    = seg * 16 + srow;
      const int lofs = seg * 512 + lane * 8;
      gll16(Ah + (size_t)r * lda + k0 + skc, A + lofs);
      gll16(Bh + (size_t)r * ldb + k0 + skc, B + lofs);
    }
  };
  auto CMP = [&](const unsigned short* A, const unsigned short* B) {
    bf16x8 aH[4], bH[4];
    #pragma unroll
    for (int t = 0; t < 4; ++t) {
      aH[t] = *(const bf16x8*)&A[(wm * 64 + t * 16 + l15) * 32 + ro];
      bH[t] = *(const bf16x8*)&B[(wn * 64 + t * 16 + l15) * 32 + ro];
    }
    #pragma unroll
    for (int rt = 0; rt < 4; ++rt)
      #pragma unroll
      for (int ct = 0; ct < 4; ++ct)
        acc[rt][ct] = mfma_bf16(aH[rt], bH[ct], acc[rt][ct]);
  };

  STG(0, AS0, BS0);
  for (int k0 = 0; k0 < K; k0 += 64) {
    __syncthreads();
    STG((k0 + 32) & Km, AS1, BS1);
    CMP(AS0, BS0);
    __syncthreads();
    STG((k0 + 64) & Km, AS0, BS0);
    CMP(AS1, BS1);
  }
}

// ---------------------------------------------------------------------------
// QK projection (split precision). grid = (M/128=64, 2*H=16), XCD-remapped:
// each XCD owns an 8-m-block chunk x all 16 z (A-panels L2-resident).
// which==0: q out [bh][t][d] bf16 hi/lo, PRE-SCALED by SC2 (exp2-domain).
// which==1: k out tile-image [bh][64 kt][4 kc][32 key][32 d-swz] bf16 hi/lo,
//           d column pre-swizzled: d' = d ^ ((key>>1 & 3)<<3).
// ---------------------------------------------------------------------------
__global__ __launch_bounds__(256) void qkm_kernel(const unsigned short* __restrict__ h_hi,
                                                  const unsigned short* __restrict__ h_lo,
                                                  const unsigned short* __restrict__ wt_hi,
                                                  const unsigned short* __restrict__ wt_lo,
                                                  unsigned short* __restrict__ q_hi,
                                                  unsigned short* __restrict__ q_lo,
                                                  unsigned short* __restrict__ k_hi,
                                                  unsigned short* __restrict__ k_lo) {
  __shared__ __align__(16) unsigned short AhS[4096], AlS[4096];
  __shared__ __align__(16) unsigned short BhS[4096], BlS[4096];
  // T1 XCD swizzle: nwg=1024, bijective
  const int bid = blockIdx.x + 64 * blockIdx.y;
  const int swz_id = (bid & 7) * 128 + (bid >> 3);
  const int m0 = ((swz_id >> 4)) << 7;
  const int z  = swz_id & 15;
  const int which = z >> 3, head = z & 7;
  f32x4 acc[4][4];
  #pragma unroll
  for (int i = 0; i < 4; ++i)
    #pragma unroll
    for (int j = 0; j < 4; ++j)
      #pragma unroll
      for (int r = 0; r < 4; ++r) acc[i][j][r] = 0.f;
  gemm128_split3(h_hi + (size_t)m0 * C_, h_lo + (size_t)m0 * C_, C_,
                 wt_hi + (size_t)z * DH * C_, wt_lo + (size_t)z * DH * C_, C_,
                 C_, acc, AhS, AlS, BhS, BlS);
  const int lane = threadIdx.x & 63, w = threadIdx.x >> 6;
  const int l15 = lane & 15, quad = lane >> 4;
  const int wm = w & 1, wn = w >> 1;
  const int bh = (m0 >> 11) * H_ + head;
  const int tbase = (m0 & (T_ - 1)) + wm * 64 + quad * 4;
  if (which == 0) {
    #pragma unroll
    for (int rt = 0; rt < 4; ++rt)
      #pragma unroll
      for (int ct = 0; ct < 4; ++ct) {
        const int d = wn * 64 + ct * 16 + l15;
        #pragma unroll
        for (int r = 0; r < 4; ++r) {
          const int t = tbase + rt * 16 + r;
          const float val = acc[rt][ct][r] * SC2;
          const unsigned short hb = f2bf(val);
          const size_t idx = ((size_t)bh * T_ + t) * DH + d;
          q_hi[idx] = hb;
          q_lo[idx] = f2bf(val - bf2f(hb));
        }
      }
  } else {
    #pragma unroll
    for (int rt = 0; rt < 4; ++rt)
      #pragma unroll
      for (int ct = 0; ct < 4; ++ct) {
        const int d = wn * 64 + ct * 16 + l15;
        #pragma unroll
        for (int r = 0; r < 4; ++r) {
          const int t = tbase + rt * 16 + r;
          const int tt = t & 31;
          const float val = acc[rt][ct][r];
          const unsigned short hb = f2bf(val);
          const size_t idx = (((size_t)bh * 64 + (t >> 5)) * 4 + (d >> 5)) * 1024
                           + (size_t)tt * 32 + ((d & 31) ^ (((tt >> 1) & 3) << 3));
          k_hi[idx] = hb;
          k_lo[idx] = f2bf(val - bf2f(hb));
        }
      }
  }
}

// ---------------------------------------------------------------------------
// V projection (plain bf16). grid = (M/128=64, H=8), XCD-remapped.
// v out tile-image [bh][64 kt][128 d][32 key-swz], key' = key ^ ((d>>1 &3)<<3).
// ---------------------------------------------------------------------------
__global__ __launch_bounds__(256) void vm_kernel(const unsigned short* __restrict__ h_hi,
                                                 const unsigned short* __restrict__ wv_hi,
                                                 unsigned short* __restrict__ vimg) {
  __shared__ __align__(16) unsigned short AS0[4096], AS1[4096];
  __shared__ __align__(16) unsigned short BS0[4096], BS1[4096];
  // T1 XCD swizzle: nwg=512, bijective
  const int bid = blockIdx.x + 64 * blockIdx.y;
  const int swz_id = (bid & 7) * 64 + (bid >> 3);
  const int m0 = (swz_id >> 3) << 7;
  const int head = swz_id & 7;
  f32x4 acc[4][4];
  #pragma unroll
  for (int i = 0; i < 4; ++i)
    #pragma unroll
    for (int j = 0; j < 4; ++j)
      #pragma unroll
      for (int r = 0; r < 4; ++r) acc[i][j][r] = 0.f;
  gemm128_db(h_hi + (size_t)m0 * C_, C_,
             wv_hi + (size_t)(16 + head) * DH * C_, C_,
             C_, acc, AS0, AS1, BS0, BS1);
  const int lane = threadIdx.x & 63, w = threadIdx.x >> 6;
  const int l15 = lane & 15, quad = lane >> 4;
  const int wm = w & 1, wn = w >> 1;
  const int bh = (m0 >> 11) * H_ + head;
  #pragma unroll
  for (int rt = 0; rt < 4; ++rt)
    #pragma unroll
    for (int ct = 0; ct < 4; ++ct) {
      const int d  = wn * 64 + ct * 16 + l15;
      const int t0 = (m0 & (T_ - 1)) + wm * 64 + rt * 16 + quad * 4;
      const int key = (t0 & 31) ^ (((d >> 1) & 3) << 3);
      ushort4 pk;
      pk.x = f2bf(acc[rt][ct][0]); pk.y = f2bf(acc[rt][ct][1]);
      pk.z = f2bf(acc[rt][ct][2]); pk.w = f2bf(acc[rt][ct][3]);
      *(ushort4*)&vimg[(((size_t)bh * 64 + (t0 >> 5)) * 128 + d) * 32 + key] = pk;
    }
}

// ---------------------------------------------------------------------------
// FF1: ff1 = bf16(relu(h2 @ w1 + b1)).  grid = (DFF/128=32, M/128=64),
// XCD-remapped (each XCD: 8 m-blocks x all 32 n; A-panels 2MB L2-resident).
// ---------------------------------------------------------------------------
__global__ __launch_bounds__(256) void ff1_kernel(const unsigned short* __restrict__ h2,
                                                  const unsigned short* __restrict__ w1t,
                                                  const float* __restrict__ b1,
                                                  unsigned short* __restrict__ ff1) {
  __shared__ __align__(16) unsigned short AS0[4096], AS1[4096];
  __shared__ __align__(16) unsigned short BS0[4096], BS1[4096];
  // T1 XCD swizzle: nwg=2048, bijective
  const int bid = blockIdx.x + 32 * blockIdx.y;
  const int swz_id = (bid & 7) * 256 + (bid >> 3);
  const int m0 = (swz_id >> 5) << 7;
  const int n0 = (swz_id & 31) << 7;
  f32x4 acc[4][4];
  #pragma unroll
  for (int i = 0; i < 4; ++i)
    #pragma unroll
    for (int j = 0; j < 4; ++j)
      #pragma unroll
      for (int r = 0; r < 4; ++r) acc[i][j][r] = 0.f;
  gemm128_db(h2 + (size_t)m0 * C_, C_,
             w1t + (size_t)n0 * C_, C_,
             C_, acc, AS0, AS1, BS0, BS1);
  const int lane = threadIdx.x & 63, w = threadIdx.x >> 6;
  const int l15 = lane & 15, quad = lane >> 4;
  const int wm = w & 1, wn = w >> 1;
  #pragma unroll
  for (int rt = 0; rt < 4; ++rt)
    #pragma unroll
    for (int ct = 0; ct < 4; ++ct) {
      const int n = n0 + wn * 64 + ct * 16 + l15;
      const float bias = b1[n];
      #pragma unroll
      for (int r = 0; r < 4; ++r) {
        const int m = m0 + wm * 64 + rt * 16 + quad * 4 + r;
        ff1[(size_t)m * DFF + n] = f2bf(fmaxf(acc[rt][ct][r] + bias, 0.f));
      }
    }
}

// ---------------------------------------------------------------------------
// FF2: out = ff1 @ w2 + b2 + xo.  grid = (C/128=8, M/128=64), XCD-remapped.
// ---------------------------------------------------------------------------
__global__ __launch_bounds__(256) void ff2_kernel(const unsigned short* __restrict__ ff1,
                                                  const unsigned short* __restrict__ w2t,
                                                  const float* __restrict__ b2,
                                                  const float* __restrict__ xo,
                                                  float* __restrict__ out) {
  __shared__ __align__(16) unsigned short AS0[4096], AS1[4096];
  __shared__ __align__(16) unsigned short BS0[4096], BS1[4096];
  // T1 XCD swizzle: nwg=512, bijective
  const int bid = blockIdx.x + 8 * blockIdx.y;
  const int swz_id = (bid & 7) * 64 + (bid >> 3);
  const int m0 = (swz_id >> 3) << 7;
  const int n0 = (swz_id & 7) << 7;
  f32x4 acc[4][4];
  #pragma unroll
  for (int i = 0; i < 4; ++i)
    #pragma unroll
    for (int j = 0; j < 4; ++j)
      #pragma unroll
      for (int r = 0; r < 4; ++r) acc[i][j][r] = 0.f;
  gemm128_db(ff1 + (size_t)m0 * DFF, DFF,
             w2t + (size_t)n0 * DFF, DFF,
             DFF, acc, AS0, AS1, BS0, BS1);
  const int lane = threadIdx.x & 63, w = threadIdx.x >> 6;
  const int l15 = lane & 15, quad = lane >> 4;
  const int wm = w & 1, wn = w >> 1;
  #pragma unroll
  for (int rt = 0; rt < 4; ++rt)
    #pragma unroll
    for (int ct = 0; ct < 4; ++ct) {
      const int n = n0 + wn * 64 + ct * 16 + l15;
      const float bias = b2[n];
      #pragma unroll
      for (int r = 0; r < 4; ++r) {
        const int m = m0 + wm * 64 + rt * 16 + quad * 4 + r;
        out[(size_t)m * C_ + n] = acc[rt][ct][r] + bias + xo[(size_t)m * C_ + n];
      }
    }
}

// ---------------------------------------------------------------------------
// MFMA flash attention (R3-v3, measured best 162.9us): 8 waves x 16 q-rows
// (512 threads) -> 16 waves/CU. Softmax at 64-key cadence (S[4] over two
// 32-key QK^T sub-tiles). K dbuf at 32-key grain, V dbuf at 64-key grain,
// 3 covered barriers/iter. In-register P transpose (no PS LDS buffer).
// grid = (T/128=16, B*H=32) = 512 blocks. XCD-aware remap.
// ---------------------------------------------------------------------------
#define BQ 128

__global__ __launch_bounds__(512, 4) void attn_kernel(
    const unsigned short* __restrict__ q_hi, const unsigned short* __restrict__ q_lo,
    const unsigned short* __restrict__ k_hi, const unsigned short* __restrict__ k_lo,
    const unsigned short* __restrict__ vimg,
    const float* __restrict__ x, float* __restrict__ xo) {
  __shared__ __align__(16) unsigned short Kh0[4096], Kh1[4096];   // 32-key K tiles
  __shared__ __align__(16) unsigned short Kl0[4096], Kl1[4096];
  __shared__ __align__(16) unsigned short Vt0[8192], Vt1[8192];   // 64-key V tiles

  // XCD-aware remap (bijective, 512 blocks = 8 XCD x 64)
  const int bid   = blockIdx.x + (T_ / BQ) * blockIdx.y;
  const int chunk = bid >> 3;
  const int bh    = (bid & 7) * 4 + (chunk >> 4);
  const int qt0   = (chunk & 15) * BQ;

  const int tid  = threadIdx.x;
  const int w    = tid >> 6;           // 0..7
  const int lane = tid & 63;
  const int l15  = lane & 15;
  const int quad = lane >> 4;
  const int swz  = (l15 >> 1) & 3;     // LDS row-dependent slot swizzle key
  // shfl source (+r): lane with l15 == quad*4+r (per-q stats live at l15==q)
  const int srcbase = quad * 20;
  // P-transpose shuffle sources (same l15, cross-quad)
  const int sA   = ((quad & 1) << 5) + l15;   // quad_s = (quad&1)*2
  const int sB   = sA + 16;                   // quad_s = (quad&1)*2 + 1
  const int bsel = (quad >> 1) & 1;           // ct-parity select

  // ---- Q fragments (pre-scaled hi/lo bf16), 16 rows per wave ----
  bf16x8 Qh[4], Ql[4];
  {
    const int row = qt0 + w * 16 + l15;
    #pragma unroll
    for (int kc = 0; kc < 4; ++kc) {
      const size_t off = ((size_t)bh * T_ + row) * DH + kc * 32 + quad * 8;
      Qh[kc] = *(const bf16x8*)(q_hi + off);
      Ql[kc] = *(const bf16x8*)(q_lo + off);
    }
  }

  f32x4 O[8];
  #pragma unroll
  for (int n = 0; n < 8; ++n)
    #pragma unroll
    for (int r = 0; r < 4; ++r) O[n][r] = 0.f;
  float m_cur = -1e30f;   // running max for q = l15 (log2 units)
  float l_cur = 0.f;

  auto STAGE_K = [&](int kt, unsigned short* KH, unsigned short* KL) {
    const size_t tb = ((size_t)bh * 64 + (kt & 63)) * 4096;
    const int ofs = w * 512 + lane * 8;
    gll16(k_hi + tb + ofs, KH + ofs);
    gll16(k_lo + tb + ofs, KL + ofs);
  };
  auto STAGE_V = [&](int jv, unsigned short* VT) {
    const size_t tb = ((size_t)bh * 64 + (jv & 31) * 2) * 4096;
    #pragma unroll
    for (int i = 0; i < 2; ++i) {
      const int o = (w * 2 + i) * 512 + lane * 8;
      gll16(vimg + tb + o, VT + o);
    }
  };
  auto QKT = [&](const unsigned short* KH, const unsigned short* KL, f32x4* Sp) {
    __builtin_amdgcn_s_setprio(1);
    #pragma unroll
    for (int kc = 0; kc < 4; ++kc)
      #pragma unroll
      for (int ct = 0; ct < 2; ++ct) {
        const int o = kc * 1024 + (ct * 16 + l15) * 32 + ((quad ^ swz) << 3);
        const bf16x8 kh = *(const bf16x8*)&KH[o];
        const bf16x8 kl = *(const bf16x8*)&KL[o];
        Sp[ct] = mfma_bf16(kl, Qh[kc], Sp[ct]);
        Sp[ct] = mfma_bf16(kh, Ql[kc], Sp[ct]);
        Sp[ct] = mfma_bf16(kh, Qh[kc], Sp[ct]);
      }
    __builtin_amdgcn_s_setprio(0);
  };

  STAGE_K(0, Kh0, Kl0);
  STAGE_K(1, Kh1, Kl1);
  STAGE_V(0, Vt0);

  for (int j = 0; j < T_ / 64; ++j) {          // 32 iters, 64 keys each
    const unsigned short* Vc = (j & 1) ? Vt1 : Vt0;
    unsigned short*       Vn = (j & 1) ? Vt0 : Vt1;

    __syncthreads();                           // B1: drains K1-restage of prev iter
    f32x4 S[4];
    #pragma unroll
    for (int ct = 0; ct < 4; ++ct)
      #pragma unroll
      for (int r = 0; r < 4; ++r) S[ct][r] = 0.f;
    // row=key=ct*16+quad*4+r, col=q=l15
    QKT(Kh0, Kl0, &S[0]);                      // keys 0..31 of this iter
    __syncthreads();                           // B2: all waves done reading K0
    STAGE_K(2 * j + 2, Kh0, Kl0);              // in flight under QKT(K1)
    STAGE_V(j + 1, Vn);
    QKT(Kh1, Kl1, &S[2]);                      // keys 32..63
    __syncthreads();                           // B3: done with K1; drains K0/V stages
    STAGE_K(2 * j + 3, Kh1, Kl1);              // in flight under softmax+PV

    // ---- per-q tile max over 64 keys: in-lane tree + 2 shfl_xor ----
    float mx = -1e30f;
    #pragma unroll
    for (int ct = 0; ct < 4; ++ct)
      mx = fmaxf(mx, fmaxf(fmaxf(S[ct][0], S[ct][1]), fmaxf(S[ct][2], S[ct][3])));
    mx = fmaxf(mx, __shfl_xor(mx, 16));
    mx = fmaxf(mx, __shfl_xor(mx, 32));

    // ---- defer-max: rescale only when running max grew by > 8 (log2) ----
    if (__any(mx > m_cur + 8.f)) {
      const float mn = fmaxf(m_cur, mx);
      const float al = exp2f(m_cur - mn);
      m_cur = mn;
      l_cur *= al;
      #pragma unroll
      for (int r = 0; r < 4; ++r) {
        const float ar = __shfl(al, srcbase + r);   // alpha for O-row q=quad*4+r
        #pragma unroll
        for (int n = 0; n < 8; ++n) O[n][r] *= ar;
      }
    }

    // ---- P = exp2(S - m), truncation-pack pairs: pu[ct*2+h] ----
    unsigned pu[8];
    float rs = 0.f;
    #pragma unroll
    for (int ct = 0; ct < 4; ++ct) {
      const float p0 = exp2f(S[ct][0] - m_cur);
      const float p1 = exp2f(S[ct][1] - m_cur);
      const float p2 = exp2f(S[ct][2] - m_cur);
      const float p3 = exp2f(S[ct][3] - m_cur);
      rs += (p0 + p1) + (p2 + p3);
      pu[ct * 2 + 0] = (__float_as_uint(p1) & 0xffff0000u) | (__float_as_uint(p0) >> 16);
      pu[ct * 2 + 1] = (__float_as_uint(p3) & 0xffff0000u) | (__float_as_uint(p2) >> 16);
    }
    rs += __shfl_xor(rs, 16);
    rs += __shfl_xor(rs, 32);
    l_cur += rs;

    // ---- in-register P transpose: dest lane needs P[q=l15][k=quad*8+j]
    //      for kgroup g; sources are lanes sA/sB (same l15, quads 2(quad&1),
    //      2(quad&1)+1), ct = 2g + bsel selected post-shuffle. ----
    bf16x8 aP[2];
    #pragma unroll
    for (int g = 0; g < 2; ++g) {
      const unsigned xA0 = (unsigned)__shfl((int)pu[4 * g + 0], sA);
      const unsigned yA0 = (unsigned)__shfl((int)pu[4 * g + 2], sA);
      const unsigned xA1 = (unsigned)__shfl((int)pu[4 * g + 1], sA);
      const unsigned yA1 = (unsigned)__shfl((int)pu[4 * g + 3], sA);
      const unsigned xB0 = (unsigned)__shfl((int)pu[4 * g + 0], sB);
      const unsigned yB0 = (unsigned)__shfl((int)pu[4 * g + 2], sB);
      const unsigned xB1 = (unsigned)__shfl((int)pu[4 * g + 1], sB);
      const unsigned yB1 = (unsigned)__shfl((int)pu[4 * g + 3], sB);
      union { unsigned u[4]; bf16x8 v; } cv;
      cv.u[0] = bsel ? yA0 : xA0;
      cv.u[1] = bsel ? yA1 : xA1;
      cv.u[2] = bsel ? yB0 : xB0;
      cv.u[3] = bsel ? yB1 : xB1;
      aP[g] = cv.v;
    }

    // ---- O += P V (both 32-key halves of Vc) ----
    __builtin_amdgcn_s_setprio(1);
    #pragma unroll
    for (int g = 0; g < 2; ++g)
      #pragma unroll
      for (int n = 0; n < 8; ++n) {
        const bf16x8 bv =
            *(const bf16x8*)&Vc[g * 4096 + (n * 16 + l15) * 32 + ((quad ^ swz) << 3)];
        O[n] = mfma_bf16(aP[g], bv, O[n]);
      }
    __builtin_amdgcn_s_setprio(0);
  }

  // ---- epilogue: xo = x + O / l  (l held at lane l15==q -> shfl to O rows) ----
  const int b = bh >> 3, hh = bh & 7;
  #pragma unroll
  for (int r = 0; r < 4; ++r) {
    const float lr = __shfl(l_cur, srcbase + r);
    const float inv_l = 1.0f / lr;
    const int t = qt0 + w * 16 + quad * 4 + r;
    const size_t xrow = ((size_t)(b * T_ + t)) * C_ + (size_t)hh * DH;
    #pragma unroll
    for (int n = 0; n < 8; ++n) {
      const int d = n * 16 + l15;
      xo[xrow + d] = x[xrow + d] + O[n][r] * inv_l;
    }
  }
}

// ---------------------------------------------------------------------------
// Workspace layout (MB offsets):
//   0-32    xo    f32 [M][C]
//   32-48   q_hi  bf16 [bh][t][d] (pre-scaled)   \
//   48-64   q_lo  bf16 [bh][t][d]                 \
//   64-80   k_hi  bf16 image [bh][64][4][32][32]   } ff1 aliases 32-96 after attn
//   80-96   k_lo  bf16 image                      /
//   96-112  vimg  bf16 image [bh][64][128][32]
//   112-128 h_hi  bf16 [M][C]
//   128-144 h_lo  bf16 [M][C]
//   144-152 w1t   bf16 [DFF][C]
//   152-160 w2t   bf16 [C][DFF]
//   160-166 wt_hi bf16 [3H][DH][C]
//   166-172 wt_lo bf16 [3H][DH][C]
// ---------------------------------------------------------------------------
extern "C" void kernel_launch(void* const* d_in, const int* in_sizes, int n_in,
                              void* d_out, int out_size, void* d_ws, size_t ws_size,
                              hipStream_t stream) {
  (void)in_sizes; (void)n_in; (void)out_size; (void)ws_size;
  const float* x     = (const float*)d_in[0];
  const float* wq    = (const float*)d_in[1];
  const float* wk    = (const float*)d_in[2];
  const float* wv    = (const float*)d_in[3];
  const float* w1    = (const float*)d_in[4];
  const float* b1    = (const float*)d_in[5];
  const float* w2    = (const float*)d_in[6];
  const float* b2    = (const float*)d_in[7];
  const float* ln1_g = (const float*)d_in[8];
  const float* ln1_b = (const float*)d_in[9];
  const float* ln2_g = (const float*)d_in[10];
  const float* ln2_b = (const float*)d_in[11];
  float* out = (float*)d_out;

  char* W = (char*)d_ws;
  float* xo = (float*)(W);
  unsigned short* q_hi  = (unsigned short*)(W + (32u  << 20));
  unsigned short* q_lo  = (unsigned short*)(W + (48u  << 20));
  unsigned short* k_hi  = (unsigned short*)(W + (64u  << 20));
  unsigned short* k_lo  = (unsigned short*)(W + (80u  << 20));
  unsigned short* vimg  = (unsigned short*)(W + (96u  << 20));
  unsigned short* ff1   = (unsigned short*)(W + (32u  << 20));   // aliases q/k
  unsigned short* h_hi  = (unsigned short*)(W + (112u << 20));
  unsigned short* h_lo  = (unsigned short*)(W + (128u << 20));
  unsigned short* w1t   = (unsigned short*)(W + (144u << 20));
  unsigned short* w2t   = (unsigned short*)(W + (152u << 20));
  unsigned short* wt_hi = (unsigned short*)(W + (160u << 20));
  unsigned short* wt_lo = (unsigned short*)(W + (166u << 20));

  cvt_t_kernel<<<dim3(DFF / 32, C_ / 32), 256, 0, stream>>>(w1, w1t, C_, DFF);
  cvt_t_kernel<<<dim3(C_ / 32, DFF / 32), 256, 0, stream>>>(w2, w2t, DFF, C_);
  cvt_qkv_kernel<<<dim3(DH / 32, C_ / 32, 24), 256, 0, stream>>>(wq, wk, wv, wt_hi, wt_lo);
  ln_kernel<<<M_, 256, 0, stream>>>(x, ln1_g, ln1_b, h_hi, h_lo);
  qkm_kernel<<<dim3(M_ / 128, 16), 256, 0, stream>>>(h_hi, h_lo, wt_hi, wt_lo,
                                                     q_hi, q_lo, k_hi, k_lo);
  vm_kernel<<<dim3(M_ / 128, H_), 256, 0, stream>>>(h_hi, wt_hi, vimg);
  attn_kernel<<<dim3(T_ / BQ, B_ * H_), 512, 0, stream>>>(q_hi, q_lo, k_hi, k_lo,
                                                          vimg, x, xo);
  ln_kernel<<<M_, 256, 0, stream>>>(xo, ln2_g, ln2_b, h_hi, h_lo);
  ff1_kernel<<<dim3(DFF / 128, M_ / 128), 256, 0, stream>>>(h_hi, w1t, b1, ff1);
  ff2_kernel<<<dim3(C_ / 128, M_ / 128), 256, 0, stream>>>(ff1, w2t, b2, xo, out);
}